// Round 1
// baseline (1197.466 us; speedup 1.0000x reference)
//
#include <hip/hip_runtime.h>

#define N_NODES 50000
#define N_EDGES 800000
#define HID 64
#define F_EDGE 16
#define LN_EPS 1e-5f

// ---------------- utility: 64-lane wave reduction ----------------
__device__ inline float wave_sum64(float v) {
    #pragma unroll
    for (int o = 32; o > 0; o >>= 1) v += __shfl_xor(v, o, 64);
    return v;
}

// ---------------- degree / norm ----------------
__global__ void k_init_deg(float* __restrict__ deg) {
    int i = blockIdx.x * blockDim.x + threadIdx.x;
    if (i < N_NODES) deg[i] = 1.0f;   // self-loop
}

__global__ void k_count_deg(const int* __restrict__ dst, float* __restrict__ deg) {
    int e = blockIdx.x * blockDim.x + threadIdx.x;
    if (e < N_EDGES) atomicAdd(&deg[dst[e]], 1.0f);
}

__global__ void k_dinv(float* __restrict__ deg) {
    int i = blockIdx.x * blockDim.x + threadIdx.x;
    if (i < N_NODES) deg[i] = rsqrtf(deg[i]);  // deg >= 1 always (self-loop)
}

// ---------------- t = hin @ W  (N x 64 @ 64 x 64) ----------------
// one wave per row; lane j computes out col j via shfl-broadcast of the row
__global__ void k_gemm64(const float* __restrict__ hin, const float* __restrict__ W,
                         float* __restrict__ t) {
    __shared__ float Ws[64 * 64];
    int tid = threadIdx.x;
    #pragma unroll
    for (int i = tid; i < 4096; i += 256) Ws[i] = W[i];
    __syncthreads();
    int wave = tid >> 6, lane = tid & 63;
    int row = blockIdx.x * 4 + wave;
    if (row >= N_NODES) return;
    float x = hin[row * 64 + lane];
    float acc = 0.f;
    #pragma unroll
    for (int k = 0; k < 64; k++)
        acc = fmaf(__shfl(x, k, 64), Ws[k * 64 + lane], acc);
    t[row * 64 + lane] = acc;
}

// ---------------- agg init: self-loop message + bias ----------------
__global__ void k_init_agg(const float* __restrict__ t, const float* __restrict__ dinv,
                           const float* __restrict__ b, float* __restrict__ agg) {
    int i = blockIdx.x * blockDim.x + threadIdx.x;
    if (i < N_NODES * 64) {
        int node = i >> 6, c = i & 63;
        float di = dinv[node];
        agg[i] = t[i] * di * di + b[c];
    }
}

// ---------------- edge scatter: one wave per edge ----------------
__global__ void k_scatter(const float* __restrict__ t, const float* __restrict__ dinv,
                          const int* __restrict__ src, const int* __restrict__ dst,
                          float* __restrict__ agg) {
    int gid = blockIdx.x * blockDim.x + threadIdx.x;
    int e = gid >> 6, c = gid & 63;
    if (e < N_EDGES) {
        int s = src[e], d = dst[e];
        float w = dinv[s] * dinv[d];
        atomicAdd(&agg[d * 64 + c], t[s * 64 + c] * w);
    }
}

// ---------------- LayerNorm + ReLU: one wave per row ----------------
__global__ void k_ln_relu(const float* __restrict__ agg, const float* __restrict__ g,
                          const float* __restrict__ b, float* __restrict__ h) {
    int gid = blockIdx.x * blockDim.x + threadIdx.x;
    int row = gid >> 6, lane = gid & 63;
    if (row >= N_NODES) return;
    float v = agg[row * 64 + lane];
    float mu = wave_sum64(v) * (1.0f / 64.0f);
    float d = v - mu;
    float var = wave_sum64(d * d) * (1.0f / 64.0f);
    float y = d * rsqrtf(var + LN_EPS) * g[lane] + b[lane];
    h[row * 64 + lane] = fmaxf(y, 0.0f);
}

// ---------------- decoder: thread per edge ----------------
__device__ inline void seg_fma(const float4* __restrict__ z4p, int n4,
                               const float* __restrict__ wbase, float* acc) {
    for (int k4 = 0; k4 < n4; k4++) {
        float4 z4 = z4p[k4];
        const float* wr = wbase + k4 * 256;   // 4 rows of 64
        #pragma unroll
        for (int j = 0; j < 64; j++) {
            acc[j] = fmaf(z4.x, wr[j],       acc[j]);
            acc[j] = fmaf(z4.y, wr[64 + j],  acc[j]);
            acc[j] = fmaf(z4.z, wr[128 + j], acc[j]);
            acc[j] = fmaf(z4.w, wr[192 + j], acc[j]);
        }
    }
}

__global__ void __launch_bounds__(256)
k_decoder(const float* __restrict__ h, const int* __restrict__ src,
          const int* __restrict__ dst, const float* __restrict__ attr,
          const float* __restrict__ W1, const float* __restrict__ b1,
          const float* __restrict__ W2, const float* __restrict__ b2,
          const float* __restrict__ W3, const float* __restrict__ b3,
          float* __restrict__ out) {
    __shared__ float W1s[144 * 64];
    __shared__ float W2s[64 * 32];
    __shared__ float W3s[32];
    __shared__ float b1s[64];
    __shared__ float b2s[32];
    int tid = threadIdx.x;
    for (int i = tid; i < 144 * 64; i += 256) W1s[i] = W1[i];
    for (int i = tid; i < 64 * 32; i += 256)  W2s[i] = W2[i];
    if (tid < 32) W3s[tid] = W3[tid];
    if (tid < 64) b1s[tid] = b1[tid];
    if (tid < 32) b2s[tid] = b2[tid];
    __syncthreads();
    float b3v = b3[0];

    int e = blockIdx.x * 256 + tid;
    if (e >= N_EDGES) return;

    int s = src[e], d = dst[e];
    float acc[64];
    #pragma unroll
    for (int j = 0; j < 64; j++) acc[j] = b1s[j];

    seg_fma((const float4*)(h + (long)s * 64), 16, &W1s[0],        acc);
    seg_fma((const float4*)(h + (long)d * 64), 16, &W1s[64 * 64],  acc);
    seg_fma((const float4*)(attr + (long)e * 16), 4, &W1s[128 * 64], acc);

    float acc2[32];
    #pragma unroll
    for (int j = 0; j < 32; j++) acc2[j] = b2s[j];
    #pragma unroll
    for (int k = 0; k < 64; k++) {
        float hk = fmaxf(acc[k], 0.0f);
        const float* wr = &W2s[k * 32];
        #pragma unroll
        for (int j = 0; j < 32; j++) acc2[j] = fmaf(hk, wr[j], acc2[j]);
    }
    float o = b3v;
    #pragma unroll
    for (int j = 0; j < 32; j++) o = fmaf(fmaxf(acc2[j], 0.0f), W3s[j], o);
    out[e] = o;
}

// ---------------- launch ----------------
extern "C" void kernel_launch(void* const* d_in, const int* in_sizes, int n_in,
                              void* d_out, int out_size, void* d_ws, size_t ws_size,
                              hipStream_t stream) {
    const float* x      = (const float*)d_in[0];
    const int*   ei     = (const int*)d_in[1];
    const float* attr   = (const float*)d_in[2];
    const float* conv_w = (const float*)d_in[3];
    const float* conv_b = (const float*)d_in[4];
    const float* ln_g   = (const float*)d_in[5];
    const float* ln_b   = (const float*)d_in[6];
    const float* dw1    = (const float*)d_in[7];
    const float* db1    = (const float*)d_in[8];
    const float* dw2    = (const float*)d_in[9];
    const float* db2    = (const float*)d_in[10];
    const float* dw3    = (const float*)d_in[11];
    const float* db3    = (const float*)d_in[12];
    float* out = (float*)d_out;

    const int* src = ei;
    const int* dst = ei + N_EDGES;

    float* dinv = (float*)d_ws;                 // N
    float* t    = dinv + N_NODES;               // N*64
    float* agg  = t + (size_t)N_NODES * 64;     // N*64
    float* h    = agg + (size_t)N_NODES * 64;   // N*64

    // degree / normalization
    k_init_deg<<<(N_NODES + 255) / 256, 256, 0, stream>>>(dinv);
    k_count_deg<<<(N_EDGES + 255) / 256, 256, 0, stream>>>(dst, dinv);
    k_dinv<<<(N_NODES + 255) / 256, 256, 0, stream>>>(dinv);

    const int row_blocks = (N_NODES + 3) / 4;          // gemm: 4 rows/block
    const int nm_blocks  = (N_NODES * 64) / 256 + 1;   // elementwise over N*64
    const int sc_blocks  = (N_EDGES * 64) / 256;       // wave per edge

    const float* hin = x;
    for (int l = 0; l < 3; l++) {
        k_gemm64<<<row_blocks, 256, 0, stream>>>(hin, conv_w + l * 4096, t);
        k_init_agg<<<nm_blocks, 256, 0, stream>>>(t, dinv, conv_b + l * 64, agg);
        k_scatter<<<sc_blocks, 256, 0, stream>>>(t, dinv, src, dst, agg);
        k_ln_relu<<<nm_blocks, 256, 0, stream>>>(agg, ln_g + l * 64, ln_b + l * 64, h);
        hin = h;
    }

    k_decoder<<<(N_EDGES + 255) / 256, 256, 0, stream>>>(
        h, src, dst, attr, dw1, db1, dw2, db2, dw3, db3, out);
}

// Round 2
// 915.697 us; speedup vs baseline: 1.3077x; 1.3077x over previous
//
#include <hip/hip_runtime.h>

#define N_NODES 50000
#define N_EDGES 800000
#define HID 64
#define F_EDGE 16
#define LN_EPS 1e-5f

// ---------------- utility: 64-lane wave reduction ----------------
__device__ inline float wave_sum64(float v) {
    #pragma unroll
    for (int o = 32; o > 0; o >>= 1) v += __shfl_xor(v, o, 64);
    return v;
}

// ---------------- CSR build ----------------
__global__ void k_zero_cnt(int* __restrict__ cnt) {
    int i = blockIdx.x * blockDim.x + threadIdx.x;
    if (i < N_NODES) cnt[i] = 0;
}

__global__ void k_count(const int* __restrict__ dst, int* __restrict__ cnt) {
    int e = blockIdx.x * blockDim.x + threadIdx.x;
    if (e < N_EDGES) atomicAdd(&cnt[dst[e]], 1);
}

__global__ void k_dinv(const int* __restrict__ cnt, float* __restrict__ dinv) {
    int i = blockIdx.x * blockDim.x + threadIdx.x;
    if (i < N_NODES) dinv[i] = rsqrtf((float)cnt[i] + 1.0f);  // +1 self-loop
}

// single-block exclusive scan of cnt -> row_ptr, cursor
__global__ void k_scan(const int* __restrict__ cnt, int* __restrict__ row_ptr,
                       int* __restrict__ cursor) {
    __shared__ int buf[1024];
    __shared__ int s_running;
    int tid = threadIdx.x;
    if (tid == 0) s_running = 0;
    __syncthreads();
    for (int base = 0; base < N_NODES; base += 1024) {
        int i = base + tid;
        int v = (i < N_NODES) ? cnt[i] : 0;
        buf[tid] = v;
        __syncthreads();
        #pragma unroll
        for (int off = 1; off < 1024; off <<= 1) {
            int add = (tid >= off) ? buf[tid - off] : 0;
            __syncthreads();
            buf[tid] += add;
            __syncthreads();
        }
        int incl = buf[tid];
        int excl = incl - v;
        int run = s_running;
        if (i < N_NODES) { row_ptr[i] = run + excl; cursor[i] = run + excl; }
        __syncthreads();
        if (tid == 1023) s_running = run + incl;
        __syncthreads();
    }
    if (tid == 0) row_ptr[N_NODES] = s_running;
}

__global__ void k_fill(const int* __restrict__ src, const int* __restrict__ dst,
                       const float* __restrict__ dinv, int* __restrict__ cursor,
                       int* __restrict__ col, float* __restrict__ ew) {
    int e = blockIdx.x * blockDim.x + threadIdx.x;
    if (e < N_EDGES) {
        int s = src[e], d = dst[e];
        int pos = atomicAdd(&cursor[d], 1);
        col[pos] = s;
        ew[pos] = dinv[s] * dinv[d];
    }
}

// ---------------- t = hin @ W : W cached in VGPRs, x via scalar loads ----------------
__global__ void __launch_bounds__(256)
k_gemm_reg(const float* __restrict__ hin, const float* __restrict__ W,
           float* __restrict__ t) {
    int lane = threadIdx.x & 63;
    int wid = (blockIdx.x * blockDim.x + threadIdx.x) >> 6;
    int nwaves = (gridDim.x * blockDim.x) >> 6;
    float w[64];
    #pragma unroll
    for (int k = 0; k < 64; k++) w[k] = W[k * 64 + lane];  // coalesced, col 'lane'
    for (int row = wid; row < N_NODES; row += nwaves) {
        int r = __builtin_amdgcn_readfirstlane(row);       // wave-uniform -> s_load
        const float* xr = hin + r * 64;
        float acc = 0.f;
        #pragma unroll
        for (int k = 0; k < 64; k++) acc = fmaf(xr[k], w[k], acc);
        t[r * 64 + lane] = acc;
    }
}

// ---------------- fused: self-loop + CSR gather + LayerNorm + ReLU ----------------
__global__ void __launch_bounds__(256)
k_gather_ln(const float* __restrict__ t, const float* __restrict__ dinv,
            const int* __restrict__ row_ptr, const int* __restrict__ col,
            const float* __restrict__ ew, const float* __restrict__ cb,
            const float* __restrict__ g, const float* __restrict__ b,
            float* __restrict__ h) {
    int gid = blockIdx.x * blockDim.x + threadIdx.x;
    int node = gid >> 6, lane = gid & 63;
    if (node >= N_NODES) return;
    int n0 = __builtin_amdgcn_readfirstlane(node);
    float di = dinv[n0];
    float acc = t[n0 * 64 + lane] * di * di + cb[lane];
    int beg = row_ptr[n0], end = row_ptr[n0 + 1];
    for (int j = beg; j < end; j++) {
        int s = col[j];                 // wave-uniform -> scalar load
        float wgt = ew[j];              // wave-uniform -> scalar load
        acc = fmaf(t[s * 64 + lane], wgt, acc);  // coalesced 256B gather
    }
    float mu = wave_sum64(acc) * (1.0f / 64.0f);
    float dd = acc - mu;
    float var = wave_sum64(dd * dd) * (1.0f / 64.0f);
    float y = dd * rsqrtf(var + LN_EPS) * g[lane] + b[lane];
    h[n0 * 64 + lane] = fmaxf(y, 0.0f);
}

// ---------------- decoder: 2 edges per thread (reuse each LDS weight read 8x) ----------------
#define E_HALF (N_EDGES / 2)

__global__ void __launch_bounds__(256, 3)
k_decoder(const float* __restrict__ h, const int* __restrict__ src,
          const int* __restrict__ dst, const float* __restrict__ attr,
          const float* __restrict__ W1, const float* __restrict__ b1,
          const float* __restrict__ W2, const float* __restrict__ b2,
          const float* __restrict__ W3, const float* __restrict__ b3,
          float* __restrict__ out) {
    __shared__ float W1s[144 * 64];
    __shared__ float W2s[64 * 32];
    __shared__ float W3s[32];
    __shared__ float b1s[64];
    __shared__ float b2s[32];
    int tid = threadIdx.x;
    for (int i = tid; i < 144 * 64; i += 256) W1s[i] = W1[i];
    for (int i = tid; i < 64 * 32; i += 256)  W2s[i] = W2[i];
    if (tid < 32) W3s[tid] = W3[tid];
    if (tid < 64) b1s[tid] = b1[tid];
    if (tid < 32) b2s[tid] = b2[tid];
    __syncthreads();
    float b3v = b3[0];

    int e0 = blockIdx.x * 256 + tid;
    if (e0 >= E_HALF) return;
    int e1 = e0 + E_HALF;

    float accA[64], accB[64];
    #pragma unroll
    for (int j = 0; j < 64; j++) { accA[j] = b1s[j]; accB[j] = b1s[j]; }

    int sA = src[e0], dA = dst[e0];
    int sB = src[e1], dB = dst[e1];

    const float4* zA[3] = { (const float4*)(h + (long)sA * 64),
                            (const float4*)(h + (long)dA * 64),
                            (const float4*)(attr + (long)e0 * 16) };
    const float4* zB[3] = { (const float4*)(h + (long)sB * 64),
                            (const float4*)(h + (long)dB * 64),
                            (const float4*)(attr + (long)e1 * 16) };
    const int n4s[3] = { 16, 16, 4 };
    const int wofs[3] = { 0, 64 * 64, 128 * 64 };

    #pragma unroll
    for (int seg = 0; seg < 3; seg++) {
        const float4* pa = zA[seg];
        const float4* pb = zB[seg];
        const float* wbase = &W1s[wofs[seg]];
        for (int k4 = 0; k4 < n4s[seg]; k4++) {
            float4 a4 = pa[k4];
            float4 b4 = pb[k4];
            const float* wr = wbase + k4 * 256;
            #pragma unroll
            for (int j = 0; j < 64; j++) {
                float w0 = wr[j], w1 = wr[64 + j], w2 = wr[128 + j], w3 = wr[192 + j];
                accA[j] = fmaf(a4.x, w0, accA[j]);
                accA[j] = fmaf(a4.y, w1, accA[j]);
                accA[j] = fmaf(a4.z, w2, accA[j]);
                accA[j] = fmaf(a4.w, w3, accA[j]);
                accB[j] = fmaf(b4.x, w0, accB[j]);
                accB[j] = fmaf(b4.y, w1, accB[j]);
                accB[j] = fmaf(b4.z, w2, accB[j]);
                accB[j] = fmaf(b4.w, w3, accB[j]);
            }
        }
    }

    float acc2A[32], acc2B[32];
    #pragma unroll
    for (int j = 0; j < 32; j++) { acc2A[j] = b2s[j]; acc2B[j] = b2s[j]; }
    #pragma unroll
    for (int k = 0; k < 64; k++) {
        float hA = fmaxf(accA[k], 0.0f);
        float hB = fmaxf(accB[k], 0.0f);
        const float* wr = &W2s[k * 32];
        #pragma unroll
        for (int j = 0; j < 32; j++) {
            float w = wr[j];
            acc2A[j] = fmaf(hA, w, acc2A[j]);
            acc2B[j] = fmaf(hB, w, acc2B[j]);
        }
    }
    float oA = b3v, oB = b3v;
    #pragma unroll
    for (int j = 0; j < 32; j++) {
        float w = W3s[j];
        oA = fmaf(fmaxf(acc2A[j], 0.0f), w, oA);
        oB = fmaf(fmaxf(acc2B[j], 0.0f), w, oB);
    }
    out[e0] = oA;
    out[e1] = oB;
}

// ---------------- launch ----------------
extern "C" void kernel_launch(void* const* d_in, const int* in_sizes, int n_in,
                              void* d_out, int out_size, void* d_ws, size_t ws_size,
                              hipStream_t stream) {
    const float* x      = (const float*)d_in[0];
    const int*   ei     = (const int*)d_in[1];
    const float* attr   = (const float*)d_in[2];
    const float* conv_w = (const float*)d_in[3];
    const float* conv_b = (const float*)d_in[4];
    const float* ln_g   = (const float*)d_in[5];
    const float* ln_b   = (const float*)d_in[6];
    const float* dw1    = (const float*)d_in[7];
    const float* db1    = (const float*)d_in[8];
    const float* dw2    = (const float*)d_in[9];
    const float* db2    = (const float*)d_in[10];
    const float* dw3    = (const float*)d_in[11];
    const float* db3    = (const float*)d_in[12];
    float* out = (float*)d_out;

    const int* src = ei;
    const int* dst = ei + N_EDGES;

    // workspace layout
    char* p = (char*)d_ws;
    float* dinv    = (float*)p; p += sizeof(float) * N_NODES;
    float* t       = (float*)p; p += sizeof(float) * (size_t)N_NODES * 64;
    float* h       = (float*)p; p += sizeof(float) * (size_t)N_NODES * 64;
    int*   cnt     = (int*)p;   p += sizeof(int) * N_NODES;
    int*   cursor  = (int*)p;   p += sizeof(int) * N_NODES;
    int*   row_ptr = (int*)p;   p += sizeof(int) * (N_NODES + 1);
    int*   col     = (int*)p;   p += sizeof(int) * N_EDGES;
    float* ew      = (float*)p; p += sizeof(float) * N_EDGES;

    const int nb_nodes = (N_NODES + 255) / 256;
    const int nb_edges = (N_EDGES + 255) / 256;

    // CSR build + normalization
    k_zero_cnt<<<nb_nodes, 256, 0, stream>>>(cnt);
    k_count<<<nb_edges, 256, 0, stream>>>(dst, cnt);
    k_dinv<<<nb_nodes, 256, 0, stream>>>(cnt, dinv);
    k_scan<<<1, 1024, 0, stream>>>(cnt, row_ptr, cursor);
    k_fill<<<nb_edges, 256, 0, stream>>>(src, dst, dinv, cursor, col, ew);

    const int gemm_blocks = 1024;                       // grid-stride waves
    const int node_wave_blocks = (N_NODES * 64) / 256 + 1;

    const float* hin = x;
    for (int l = 0; l < 3; l++) {
        k_gemm_reg<<<gemm_blocks, 256, 0, stream>>>(hin, conv_w + l * 4096, t);
        k_gather_ln<<<node_wave_blocks, 256, 0, stream>>>(
            t, dinv, row_ptr, col, ew, conv_b + l * 64,
            ln_g + l * 64, ln_b + l * 64, h);
        hin = h;
    }

    k_decoder<<<(E_HALF + 255) / 256, 256, 0, stream>>>(
        h, src, dst, attr, dw1, db1, dw2, db2, dw3, db3, out);
}

// Round 3
// 797.975 us; speedup vs baseline: 1.5006x; 1.1475x over previous
//
#include <hip/hip_runtime.h>

#define N_NODES 50000
#define N_EDGES 800000
#define HID 64
#define F_EDGE 16
#define LN_EPS 1e-5f

// ---------------- utility: 64-lane wave reduction ----------------
__device__ inline float wave_sum64(float v) {
    #pragma unroll
    for (int o = 32; o > 0; o >>= 1) v += __shfl_xor(v, o, 64);
    return v;
}

// ---------------- CSR build ----------------
__global__ void k_zero_cnt(int* __restrict__ cnt) {
    int i = blockIdx.x * blockDim.x + threadIdx.x;
    if (i < N_NODES) cnt[i] = 0;
}

__global__ void k_count(const int* __restrict__ dst, int* __restrict__ cnt) {
    int e = blockIdx.x * blockDim.x + threadIdx.x;
    if (e < N_EDGES) atomicAdd(&cnt[dst[e]], 1);
}

__global__ void k_dinv(const int* __restrict__ cnt, float* __restrict__ dinv) {
    int i = blockIdx.x * blockDim.x + threadIdx.x;
    if (i < N_NODES) dinv[i] = rsqrtf((float)cnt[i] + 1.0f);  // +1 self-loop
}

// single-block scan, shfl-based (2 barriers per 1024-chunk, not 20)
__global__ void k_scan(const int* __restrict__ cnt, int* __restrict__ row_ptr,
                       int* __restrict__ cursor) {
    __shared__ int wsum[16];
    __shared__ int s_running;
    int tid = threadIdx.x, lane = tid & 63, w = tid >> 6;
    if (tid == 0) s_running = 0;
    __syncthreads();
    for (int base = 0; base < N_NODES; base += 1024) {
        int i = base + tid;
        int v = (i < N_NODES) ? cnt[i] : 0;
        int isc = v;
        #pragma unroll
        for (int o = 1; o < 64; o <<= 1) {
            int n = __shfl_up(isc, o, 64);
            if (lane >= o) isc += n;
        }
        if (lane == 63) wsum[w] = isc;
        __syncthreads();
        int woff = 0;
        #pragma unroll
        for (int k = 0; k < 16; k++) woff += (k < w) ? wsum[k] : 0;
        int run = s_running;
        int excl = run + woff + isc - v;
        if (i < N_NODES) { row_ptr[i] = excl; cursor[i] = excl; }
        __syncthreads();
        if (tid == 1023) s_running = run + woff + isc;
        __syncthreads();
    }
    __syncthreads();
    if (tid == 0) row_ptr[N_NODES] = s_running;
}

__global__ void k_fill(const int* __restrict__ src, const int* __restrict__ dst,
                       const float* __restrict__ dinv, int* __restrict__ cursor,
                       int* __restrict__ col, float* __restrict__ ew) {
    int e = blockIdx.x * blockDim.x + threadIdx.x;
    if (e < N_EDGES) {
        int s = src[e], d = dst[e];
        int pos = atomicAdd(&cursor[d], 1);
        col[pos] = s;
        ew[pos] = dinv[s] * dinv[d];
    }
}

// ---------------- out = hin @ W (+bias) : W col cached in VGPRs, x via s_load ----------------
__global__ void __launch_bounds__(256)
k_gemm_reg(const float* __restrict__ hin, const float* __restrict__ W,
           const float* __restrict__ bias, float* __restrict__ out) {
    int lane = threadIdx.x & 63;
    int wid = (blockIdx.x * blockDim.x + threadIdx.x) >> 6;
    int nwaves = (gridDim.x * blockDim.x) >> 6;
    float w[64];
    #pragma unroll
    for (int k = 0; k < 64; k++) w[k] = W[k * 64 + lane];
    float binit = bias ? bias[lane] : 0.0f;
    for (int row = wid; row < N_NODES; row += nwaves) {
        int r = __builtin_amdgcn_readfirstlane(row);
        const float* xr = hin + r * 64;
        float acc = binit;
        #pragma unroll
        for (int k = 0; k < 64; k++) acc = fmaf(xr[k], w[k], acc);
        out[r * 64 + lane] = acc;
    }
}

// ---------------- fused: self-loop + CSR gather + LayerNorm + ReLU ----------------
// wave per node; 4 edges in flight (16 lanes each), float4 channels
__global__ void __launch_bounds__(256)
k_gather_ln(const float* __restrict__ t, const float* __restrict__ dinv,
            const int* __restrict__ row_ptr, const int* __restrict__ col,
            const float* __restrict__ ew, const float* __restrict__ cb,
            const float* __restrict__ g, const float* __restrict__ b,
            float* __restrict__ h) {
    int gid = blockIdx.x * blockDim.x + threadIdx.x;
    int node = gid >> 6, lane = gid & 63;
    if (node >= N_NODES) return;
    int n0 = __builtin_amdgcn_readfirstlane(node);
    int q = lane >> 4, c4 = lane & 15;
    const float4* t4 = (const float4*)t;

    float di = dinv[n0];
    float4 acc = make_float4(0.f, 0.f, 0.f, 0.f);
    if (q == 0) {
        float4 tv = t4[(size_t)n0 * 16 + c4];
        float4 cbv = ((const float4*)cb)[c4];
        float s2 = di * di;
        acc.x = fmaf(tv.x, s2, cbv.x);
        acc.y = fmaf(tv.y, s2, cbv.y);
        acc.z = fmaf(tv.z, s2, cbv.z);
        acc.w = fmaf(tv.w, s2, cbv.w);
    }
    int beg = row_ptr[n0], end = row_ptr[n0 + 1];
    for (int j = beg + q; j < end; j += 4) {
        int s = col[j];
        float wgt = ew[j];
        float4 tv = t4[(size_t)s * 16 + c4];
        acc.x = fmaf(tv.x, wgt, acc.x);
        acc.y = fmaf(tv.y, wgt, acc.y);
        acc.z = fmaf(tv.z, wgt, acc.z);
        acc.w = fmaf(tv.w, wgt, acc.w);
    }
    // reduce across the 4 edge-slots (lanes differing in bits 4,5)
    #pragma unroll
    for (int o = 16; o <= 32; o <<= 1) {
        acc.x += __shfl_xor(acc.x, o, 64);
        acc.y += __shfl_xor(acc.y, o, 64);
        acc.z += __shfl_xor(acc.z, o, 64);
        acc.w += __shfl_xor(acc.w, o, 64);
    }
    // LayerNorm: each channel appears 4x across the wave -> divide by 256
    float ps = acc.x + acc.y + acc.z + acc.w;
    float mu = wave_sum64(ps) * (1.0f / 256.0f);
    float4 d = make_float4(acc.x - mu, acc.y - mu, acc.z - mu, acc.w - mu);
    float vps = d.x * d.x + d.y * d.y + d.z * d.z + d.w * d.w;
    float var = wave_sum64(vps) * (1.0f / 256.0f);
    float rstd = rsqrtf(var + LN_EPS);
    if (q == 0) {
        float4 gv = ((const float4*)g)[c4];
        float4 bv = ((const float4*)b)[c4];
        float4 y;
        y.x = fmaxf(fmaf(d.x * rstd, gv.x, bv.x), 0.f);
        y.y = fmaxf(fmaf(d.y * rstd, gv.y, bv.y), 0.f);
        y.z = fmaxf(fmaf(d.z * rstd, gv.z, bv.z), 0.f);
        y.w = fmaxf(fmaf(d.w * rstd, gv.w, bv.w), 0.f);
        ((float4*)h)[(size_t)n0 * 16 + c4] = y;
    }
}

// ---------------- decoder ----------------
// acc[j] = P[src][j] + Q[dst][j] + attr@W1c ; relu ; @W2 ; relu ; @W3
__device__ inline void tile4(const float4 a, const float4 w0, const float4 w1,
                             const float4 w2, const float4 w3, float* acc) {
    acc[0] = fmaf(a.x, w0.x, acc[0]); acc[0] = fmaf(a.y, w1.x, acc[0]);
    acc[0] = fmaf(a.z, w2.x, acc[0]); acc[0] = fmaf(a.w, w3.x, acc[0]);
    acc[1] = fmaf(a.x, w0.y, acc[1]); acc[1] = fmaf(a.y, w1.y, acc[1]);
    acc[1] = fmaf(a.z, w2.y, acc[1]); acc[1] = fmaf(a.w, w3.y, acc[1]);
    acc[2] = fmaf(a.x, w0.z, acc[2]); acc[2] = fmaf(a.y, w1.z, acc[2]);
    acc[2] = fmaf(a.z, w2.z, acc[2]); acc[2] = fmaf(a.w, w3.z, acc[2]);
    acc[3] = fmaf(a.x, w0.w, acc[3]); acc[3] = fmaf(a.y, w1.w, acc[3]);
    acc[3] = fmaf(a.z, w2.w, acc[3]); acc[3] = fmaf(a.w, w3.w, acc[3]);
}

__global__ void __launch_bounds__(256, 1)
k_decoder(const float* __restrict__ P, const float* __restrict__ Q,
          const int* __restrict__ src, const int* __restrict__ dst,
          const float* __restrict__ attr,
          const float* __restrict__ W1c,
          const float* __restrict__ W2, const float* __restrict__ b2,
          const float* __restrict__ W3, const float* __restrict__ b3,
          float* __restrict__ out) {
    __shared__ float W1cs[16 * 64];
    __shared__ float W2s[64 * 32];
    __shared__ float W3s[32];
    __shared__ float b2s[32];
    int tid = threadIdx.x;
    for (int i = tid; i < 16 * 64; i += 256) W1cs[i] = W1c[i];
    for (int i = tid; i < 64 * 32; i += 256) W2s[i] = W2[i];
    if (tid < 32) W3s[tid] = W3[tid];
    if (tid < 32) b2s[tid] = b2[tid];
    __syncthreads();
    float b3v = b3[0];

    int e0 = blockIdx.x * 512 + tid;
    if (e0 >= N_EDGES) return;
    int e1 = e0 + 256;
    bool hasB = (e1 < N_EDGES);
    int e1c = hasB ? e1 : e0;

    int sA = src[e0], dA = dst[e0];
    int sB = src[e1c], dB = dst[e1c];

    // prefetch attr
    const float4* atA = (const float4*)(attr + (size_t)e0 * 16);
    const float4* atB = (const float4*)(attr + (size_t)e1c * 16);
    float4 aA[4], aB[4];
    #pragma unroll
    for (int k = 0; k < 4; k++) { aA[k] = atA[k]; aB[k] = atB[k]; }

    // acc = P[s] + Q[d]
    float accA[64], accB[64];
    const float4* PA = (const float4*)(P + (size_t)sA * 64);
    const float4* QA = (const float4*)(Q + (size_t)dA * 64);
    const float4* PB = (const float4*)(P + (size_t)sB * 64);
    const float4* QB = (const float4*)(Q + (size_t)dB * 64);
    #pragma unroll
    for (int c = 0; c < 16; c++) {
        float4 pa = PA[c], qa = QA[c];
        float4 pb = PB[c], qb = QB[c];
        accA[4*c+0] = pa.x + qa.x; accA[4*c+1] = pa.y + qa.y;
        accA[4*c+2] = pa.z + qa.z; accA[4*c+3] = pa.w + qa.w;
        accB[4*c+0] = pb.x + qb.x; accB[4*c+1] = pb.y + qb.y;
        accB[4*c+2] = pb.z + qb.z; accB[4*c+3] = pb.w + qb.w;
    }

    // + attr @ W1c  (16x64)
    #pragma unroll
    for (int k4 = 0; k4 < 4; k4++) {
        const float* w0r = &W1cs[(k4 * 4 + 0) * 64];
        const float* w1r = &W1cs[(k4 * 4 + 1) * 64];
        const float* w2r = &W1cs[(k4 * 4 + 2) * 64];
        const float* w3r = &W1cs[(k4 * 4 + 3) * 64];
        float4 a = aA[k4], bb = aB[k4];
        #pragma unroll
        for (int j4 = 0; j4 < 16; j4++) {
            float4 w0 = *(const float4*)(w0r + j4 * 4);
            float4 w1 = *(const float4*)(w1r + j4 * 4);
            float4 w2 = *(const float4*)(w2r + j4 * 4);
            float4 w3 = *(const float4*)(w3r + j4 * 4);
            tile4(a, w0, w1, w2, w3, &accA[j4 * 4]);
            tile4(bb, w0, w1, w2, w3, &accB[j4 * 4]);
        }
    }

    // layer 2: relu(acc) @ W2  (64x32)
    float acc2A[32], acc2B[32];
    #pragma unroll
    for (int j = 0; j < 32; j++) { acc2A[j] = b2s[j]; acc2B[j] = b2s[j]; }
    for (int k4 = 0; k4 < 16; k4++) {
        const float* w0r = &W2s[(k4 * 4 + 0) * 32];
        const float* w1r = &W2s[(k4 * 4 + 1) * 32];
        const float* w2r = &W2s[(k4 * 4 + 2) * 32];
        const float* w3r = &W2s[(k4 * 4 + 3) * 32];
        float4 hA, hB;
        hA.x = fmaxf(accA[4*k4+0], 0.f); hA.y = fmaxf(accA[4*k4+1], 0.f);
        hA.z = fmaxf(accA[4*k4+2], 0.f); hA.w = fmaxf(accA[4*k4+3], 0.f);
        hB.x = fmaxf(accB[4*k4+0], 0.f); hB.y = fmaxf(accB[4*k4+1], 0.f);
        hB.z = fmaxf(accB[4*k4+2], 0.f); hB.w = fmaxf(accB[4*k4+3], 0.f);
        #pragma unroll
        for (int j4 = 0; j4 < 8; j4++) {
            float4 w0 = *(const float4*)(w0r + j4 * 4);
            float4 w1 = *(const float4*)(w1r + j4 * 4);
            float4 w2 = *(const float4*)(w2r + j4 * 4);
            float4 w3 = *(const float4*)(w3r + j4 * 4);
            tile4(hA, w0, w1, w2, w3, &acc2A[j4 * 4]);
            tile4(hB, w0, w1, w2, w3, &acc2B[j4 * 4]);
        }
    }

    // layer 3
    float oA = b3v, oB = b3v;
    #pragma unroll
    for (int j4 = 0; j4 < 8; j4++) {
        float4 w = *(const float4*)&W3s[j4 * 4];
        oA = fmaf(fmaxf(acc2A[4*j4+0], 0.f), w.x, oA);
        oA = fmaf(fmaxf(acc2A[4*j4+1], 0.f), w.y, oA);
        oA = fmaf(fmaxf(acc2A[4*j4+2], 0.f), w.z, oA);
        oA = fmaf(fmaxf(acc2A[4*j4+3], 0.f), w.w, oA);
        oB = fmaf(fmaxf(acc2B[4*j4+0], 0.f), w.x, oB);
        oB = fmaf(fmaxf(acc2B[4*j4+1], 0.f), w.y, oB);
        oB = fmaf(fmaxf(acc2B[4*j4+2], 0.f), w.z, oB);
        oB = fmaf(fmaxf(acc2B[4*j4+3], 0.f), w.w, oB);
    }
    out[e0] = oA;
    if (hasB) out[e1] = oB;
}

// ---------------- launch ----------------
extern "C" void kernel_launch(void* const* d_in, const int* in_sizes, int n_in,
                              void* d_out, int out_size, void* d_ws, size_t ws_size,
                              hipStream_t stream) {
    const float* x      = (const float*)d_in[0];
    const int*   ei     = (const int*)d_in[1];
    const float* attr   = (const float*)d_in[2];
    const float* conv_w = (const float*)d_in[3];
    const float* conv_b = (const float*)d_in[4];
    const float* ln_g   = (const float*)d_in[5];
    const float* ln_b   = (const float*)d_in[6];
    const float* dw1    = (const float*)d_in[7];
    const float* db1    = (const float*)d_in[8];
    const float* dw2    = (const float*)d_in[9];
    const float* db2    = (const float*)d_in[10];
    const float* dw3    = (const float*)d_in[11];
    const float* db3    = (const float*)d_in[12];
    float* out = (float*)d_out;

    const int* src = ei;
    const int* dst = ei + N_EDGES;

    // workspace layout (t doubles as P after the conv layers)
    char* p = (char*)d_ws;
    float* dinv    = (float*)p; p += sizeof(float) * N_NODES;
    float* t       = (float*)p; p += sizeof(float) * (size_t)N_NODES * 64;
    float* h       = (float*)p; p += sizeof(float) * (size_t)N_NODES * 64;
    float* Q       = (float*)p; p += sizeof(float) * (size_t)N_NODES * 64;
    int*   cnt     = (int*)p;   p += sizeof(int) * N_NODES;
    int*   cursor  = (int*)p;   p += sizeof(int) * N_NODES;
    int*   row_ptr = (int*)p;   p += sizeof(int) * (N_NODES + 1);
    int*   col     = (int*)p;   p += sizeof(int) * N_EDGES;
    float* ew      = (float*)p; p += sizeof(float) * N_EDGES;

    const int nb_nodes = (N_NODES + 255) / 256;
    const int nb_edges = (N_EDGES + 255) / 256;

    k_zero_cnt<<<nb_nodes, 256, 0, stream>>>(cnt);
    k_count<<<nb_edges, 256, 0, stream>>>(dst, cnt);
    k_dinv<<<nb_nodes, 256, 0, stream>>>(cnt, dinv);
    k_scan<<<1, 1024, 0, stream>>>(cnt, row_ptr, cursor);
    k_fill<<<nb_edges, 256, 0, stream>>>(src, dst, dinv, cursor, col, ew);

    const int gemm_blocks = 1024;
    const int gather_blocks = N_NODES / 4;   // wave per node, 4 waves/block

    const float* hin = x;
    for (int l = 0; l < 3; l++) {
        k_gemm_reg<<<gemm_blocks, 256, 0, stream>>>(hin, conv_w + l * 4096, nullptr, t);
        k_gather_ln<<<gather_blocks, 256, 0, stream>>>(
            t, dinv, row_ptr, col, ew, conv_b + l * 64,
            ln_g + l * 64, ln_b + l * 64, h);
        hin = h;
    }

    // P = h @ W1[0:64] + b1  (into t) ;  Q = h @ W1[64:128]
    k_gemm_reg<<<gemm_blocks, 256, 0, stream>>>(h, dw1, db1, t);
    k_gemm_reg<<<gemm_blocks, 256, 0, stream>>>(h, dw1 + 64 * 64, nullptr, Q);

    k_decoder<<<(N_EDGES + 511) / 512, 256, 0, stream>>>(
        t, Q, src, dst, attr, dw1 + 128 * 64, dw2, db2, dw3, db3, out);
}

// Round 4
// 577.668 us; speedup vs baseline: 2.0729x; 1.3814x over previous
//
#include <hip/hip_runtime.h>

#define N_NODES 50000
#define N_EDGES 800000
#define HID 64
#define F_EDGE 16
#define LN_EPS 1e-5f

// ---------------- utility: 64-lane wave reduction ----------------
__device__ inline float wave_sum64(float v) {
    #pragma unroll
    for (int o = 32; o > 0; o >>= 1) v += __shfl_xor(v, o, 64);
    return v;
}

// ---------------- CSR build ----------------
__global__ void k_zero_cnt(int* __restrict__ cnt) {
    int i = blockIdx.x * blockDim.x + threadIdx.x;
    if (i < N_NODES) cnt[i] = 0;
}

__global__ void k_count(const int* __restrict__ dst, int* __restrict__ cnt) {
    int e = blockIdx.x * blockDim.x + threadIdx.x;
    if (e < N_EDGES) atomicAdd(&cnt[dst[e]], 1);
}

__global__ void k_dinv(const int* __restrict__ cnt, float* __restrict__ dinv) {
    int i = blockIdx.x * blockDim.x + threadIdx.x;
    if (i < N_NODES) dinv[i] = rsqrtf((float)cnt[i] + 1.0f);  // +1 self-loop
}

// single-block scan, shfl-based
__global__ void k_scan(const int* __restrict__ cnt, int* __restrict__ row_ptr,
                       int* __restrict__ cursor) {
    __shared__ int wsum[16];
    __shared__ int s_running;
    int tid = threadIdx.x, lane = tid & 63, w = tid >> 6;
    if (tid == 0) s_running = 0;
    __syncthreads();
    for (int base = 0; base < N_NODES; base += 1024) {
        int i = base + tid;
        int v = (i < N_NODES) ? cnt[i] : 0;
        int isc = v;
        #pragma unroll
        for (int o = 1; o < 64; o <<= 1) {
            int n = __shfl_up(isc, o, 64);
            if (lane >= o) isc += n;
        }
        if (lane == 63) wsum[w] = isc;
        __syncthreads();
        int woff = 0;
        #pragma unroll
        for (int k = 0; k < 16; k++) woff += (k < w) ? wsum[k] : 0;
        int run = s_running;
        int excl = run + woff + isc - v;
        if (i < N_NODES) { row_ptr[i] = excl; cursor[i] = excl; }
        __syncthreads();
        if (tid == 1023) s_running = run + woff + isc;
        __syncthreads();
    }
    __syncthreads();
    if (tid == 0) row_ptr[N_NODES] = s_running;
}

__global__ void k_fill(const int* __restrict__ src, const int* __restrict__ dst,
                       const float* __restrict__ dinv, int* __restrict__ cursor,
                       int* __restrict__ col, float* __restrict__ ew) {
    int e = blockIdx.x * blockDim.x + threadIdx.x;
    if (e < N_EDGES) {
        int s = src[e], d = dst[e];
        int pos = atomicAdd(&cursor[d], 1);
        col[pos] = s;
        ew[pos] = dinv[s] * dinv[d];
    }
}

// ---------------- out = hin @ W (+bias) : W col cached in VGPRs, x via s_load ----------------
__global__ void __launch_bounds__(256)
k_gemm_reg(const float* __restrict__ hin, const float* __restrict__ W,
           const float* __restrict__ bias, float* __restrict__ out) {
    int lane = threadIdx.x & 63;
    int wid = (blockIdx.x * blockDim.x + threadIdx.x) >> 6;
    int nwaves = (gridDim.x * blockDim.x) >> 6;
    float w[64];
    #pragma unroll
    for (int k = 0; k < 64; k++) w[k] = W[k * 64 + lane];
    float binit = bias ? bias[lane] : 0.0f;
    for (int row = wid; row < N_NODES; row += nwaves) {
        int r = __builtin_amdgcn_readfirstlane(row);
        const float* xr = hin + r * 64;
        float acc = binit;
        #pragma unroll
        for (int k = 0; k < 64; k++) acc = fmaf(xr[k], w[k], acc);
        out[r * 64 + lane] = acc;
    }
}

// ---------------- fused: self-loop + CSR gather + LayerNorm + ReLU ----------------
__global__ void __launch_bounds__(256)
k_gather_ln(const float* __restrict__ t, const float* __restrict__ dinv,
            const int* __restrict__ row_ptr, const int* __restrict__ col,
            const float* __restrict__ ew, const float* __restrict__ cb,
            const float* __restrict__ g, const float* __restrict__ b,
            float* __restrict__ h) {
    int gid = blockIdx.x * blockDim.x + threadIdx.x;
    int node = gid >> 6, lane = gid & 63;
    if (node >= N_NODES) return;
    int n0 = __builtin_amdgcn_readfirstlane(node);
    int q = lane >> 4, c4 = lane & 15;
    const float4* t4 = (const float4*)t;

    float di = dinv[n0];
    float4 acc = make_float4(0.f, 0.f, 0.f, 0.f);
    if (q == 0) {
        float4 tv = t4[(size_t)n0 * 16 + c4];
        float4 cbv = ((const float4*)cb)[c4];
        float s2 = di * di;
        acc.x = fmaf(tv.x, s2, cbv.x);
        acc.y = fmaf(tv.y, s2, cbv.y);
        acc.z = fmaf(tv.z, s2, cbv.z);
        acc.w = fmaf(tv.w, s2, cbv.w);
    }
    int beg = row_ptr[n0], end = row_ptr[n0 + 1];
    for (int j = beg + q; j < end; j += 4) {
        int s = col[j];
        float wgt = ew[j];
        float4 tv = t4[(size_t)s * 16 + c4];
        acc.x = fmaf(tv.x, wgt, acc.x);
        acc.y = fmaf(tv.y, wgt, acc.y);
        acc.z = fmaf(tv.z, wgt, acc.z);
        acc.w = fmaf(tv.w, wgt, acc.w);
    }
    #pragma unroll
    for (int o = 16; o <= 32; o <<= 1) {
        acc.x += __shfl_xor(acc.x, o, 64);
        acc.y += __shfl_xor(acc.y, o, 64);
        acc.z += __shfl_xor(acc.z, o, 64);
        acc.w += __shfl_xor(acc.w, o, 64);
    }
    float ps = acc.x + acc.y + acc.z + acc.w;
    float mu = wave_sum64(ps) * (1.0f / 256.0f);
    float4 d = make_float4(acc.x - mu, acc.y - mu, acc.z - mu, acc.w - mu);
    float vps = d.x * d.x + d.y * d.y + d.z * d.z + d.w * d.w;
    float var = wave_sum64(vps) * (1.0f / 256.0f);
    float rstd = rsqrtf(var + LN_EPS);
    if (q == 0) {
        float4 gv = ((const float4*)g)[c4];
        float4 bv = ((const float4*)b)[c4];
        float4 y;
        y.x = fmaxf(fmaf(d.x * rstd, gv.x, bv.x), 0.f);
        y.y = fmaxf(fmaf(d.y * rstd, gv.y, bv.y), 0.f);
        y.z = fmaxf(fmaf(d.z * rstd, gv.z, bv.z), 0.f);
        y.w = fmaxf(fmaf(d.w * rstd, gv.w, bv.w), 0.f);
        ((float4*)h)[(size_t)n0 * 16 + c4] = y;
    }
}

// ---------------- decoder: 1 edge/thread, weights via wave-uniform s_load ----------------
// RULE: acc[]/acc2[] indices are compile-time constants everywhere (no scratch).
__global__ void __launch_bounds__(256)
k_decoder(const float* __restrict__ P, const float* __restrict__ Q,
          const int* __restrict__ src, const int* __restrict__ dst,
          const float* __restrict__ attr,
          const float* __restrict__ W1c,
          const float* __restrict__ W2, const float* __restrict__ b2,
          const float* __restrict__ W3, const float* __restrict__ b3,
          float* __restrict__ out) {
    int e = blockIdx.x * blockDim.x + threadIdx.x;
    if (e >= N_EDGES) return;
    int s = src[e], d = dst[e];

    // attr prefetch (per-thread vector loads)
    const float4* ap = (const float4*)(attr + (size_t)e * 16);
    float4 av0 = ap[0], av1 = ap[1], av2 = ap[2], av3 = ap[3];

    // acc = P[s] + Q[d]   (b1 already folded into P)
    float acc[64];
    const float4* Pp = (const float4*)(P + (size_t)s * 64);
    const float4* Qp = (const float4*)(Q + (size_t)d * 64);
    #pragma unroll
    for (int c = 0; c < 16; c++) {
        float4 pv = Pp[c], qv = Qp[c];
        acc[4 * c + 0] = pv.x + qv.x;
        acc[4 * c + 1] = pv.y + qv.y;
        acc[4 * c + 2] = pv.z + qv.z;
        acc[4 * c + 3] = pv.w + qv.w;
    }

    // + attr @ W1c (16x64); W1c reads are wave-uniform -> scalar loads
    #pragma unroll
    for (int j = 0; j < 64; j++) {
        float a = acc[j];
        a = fmaf(av0.x, W1c[0 * 64 + j], a);
        a = fmaf(av0.y, W1c[1 * 64 + j], a);
        a = fmaf(av0.z, W1c[2 * 64 + j], a);
        a = fmaf(av0.w, W1c[3 * 64 + j], a);
        a = fmaf(av1.x, W1c[4 * 64 + j], a);
        a = fmaf(av1.y, W1c[5 * 64 + j], a);
        a = fmaf(av1.z, W1c[6 * 64 + j], a);
        a = fmaf(av1.w, W1c[7 * 64 + j], a);
        a = fmaf(av2.x, W1c[8 * 64 + j], a);
        a = fmaf(av2.y, W1c[9 * 64 + j], a);
        a = fmaf(av2.z, W1c[10 * 64 + j], a);
        a = fmaf(av2.w, W1c[11 * 64 + j], a);
        a = fmaf(av3.x, W1c[12 * 64 + j], a);
        a = fmaf(av3.y, W1c[13 * 64 + j], a);
        a = fmaf(av3.z, W1c[14 * 64 + j], a);
        a = fmaf(av3.w, W1c[15 * 64 + j], a);
        acc[j] = fmaxf(a, 0.0f);   // ReLU fused
    }

    // layer 2: acc2 = relu(acc) @ W2 (64x32), scalar-load weights, fully unrolled
    float acc2[32];
    #pragma unroll
    for (int j = 0; j < 32; j++) acc2[j] = b2[j];
    #pragma unroll
    for (int k = 0; k < 64; k++) {
        float hk = acc[k];
        #pragma unroll
        for (int j = 0; j < 32; j++)
            acc2[j] = fmaf(hk, W2[k * 32 + j], acc2[j]);
    }

    // layer 3
    float o = b3[0];
    #pragma unroll
    for (int j = 0; j < 32; j++)
        o = fmaf(fmaxf(acc2[j], 0.0f), W3[j], o);
    out[e] = o;
}

// ---------------- launch ----------------
extern "C" void kernel_launch(void* const* d_in, const int* in_sizes, int n_in,
                              void* d_out, int out_size, void* d_ws, size_t ws_size,
                              hipStream_t stream) {
    const float* x      = (const float*)d_in[0];
    const int*   ei     = (const int*)d_in[1];
    const float* attr   = (const float*)d_in[2];
    const float* conv_w = (const float*)d_in[3];
    const float* conv_b = (const float*)d_in[4];
    const float* ln_g   = (const float*)d_in[5];
    const float* ln_b   = (const float*)d_in[6];
    const float* dw1    = (const float*)d_in[7];
    const float* db1    = (const float*)d_in[8];
    const float* dw2    = (const float*)d_in[9];
    const float* db2    = (const float*)d_in[10];
    const float* dw3    = (const float*)d_in[11];
    const float* db3    = (const float*)d_in[12];
    float* out = (float*)d_out;

    const int* src = ei;
    const int* dst = ei + N_EDGES;

    char* p = (char*)d_ws;
    float* dinv    = (float*)p; p += sizeof(float) * N_NODES;
    float* t       = (float*)p; p += sizeof(float) * (size_t)N_NODES * 64;
    float* h       = (float*)p; p += sizeof(float) * (size_t)N_NODES * 64;
    float* Q       = (float*)p; p += sizeof(float) * (size_t)N_NODES * 64;
    int*   cnt     = (int*)p;   p += sizeof(int) * N_NODES;
    int*   cursor  = (int*)p;   p += sizeof(int) * N_NODES;
    int*   row_ptr = (int*)p;   p += sizeof(int) * (N_NODES + 1);
    int*   col     = (int*)p;   p += sizeof(int) * N_EDGES;
    float* ew      = (float*)p; p += sizeof(float) * N_EDGES;

    const int nb_nodes = (N_NODES + 255) / 256;
    const int nb_edges = (N_EDGES + 255) / 256;

    k_zero_cnt<<<nb_nodes, 256, 0, stream>>>(cnt);
    k_count<<<nb_edges, 256, 0, stream>>>(dst, cnt);
    k_dinv<<<nb_nodes, 256, 0, stream>>>(cnt, dinv);
    k_scan<<<1, 1024, 0, stream>>>(cnt, row_ptr, cursor);
    k_fill<<<nb_edges, 256, 0, stream>>>(src, dst, dinv, cursor, col, ew);

    const int gemm_blocks = 1024;
    const int gather_blocks = N_NODES / 4;

    const float* hin = x;
    for (int l = 0; l < 3; l++) {
        k_gemm_reg<<<gemm_blocks, 256, 0, stream>>>(hin, conv_w + l * 4096, nullptr, t);
        k_gather_ln<<<gather_blocks, 256, 0, stream>>>(
            t, dinv, row_ptr, col, ew, conv_b + l * 64,
            ln_g + l * 64, ln_b + l * 64, h);
        hin = h;
    }

    // P = h @ W1[0:64] + b1  (into t) ;  Q = h @ W1[64:128]
    k_gemm_reg<<<gemm_blocks, 256, 0, stream>>>(h, dw1, db1, t);
    k_gemm_reg<<<gemm_blocks, 256, 0, stream>>>(h, dw1 + 64 * 64, nullptr, Q);

    k_decoder<<<nb_edges, 256, 0, stream>>>(
        t, Q, src, dst, attr, dw1 + 128 * 64, dw2, db2, dw3, db3, out);
}

// Round 5
// 524.118 us; speedup vs baseline: 2.2847x; 1.1022x over previous
//
#include <hip/hip_runtime.h>

#define N_NODES 50000
#define N_EDGES 800000
#define HID 64
#define F_EDGE 16
#define LN_EPS 1e-5f
#define SCAN_BLOCKS ((N_NODES + 255) / 256)   // 196

// ---------------- utility: 64-lane wave reduction ----------------
__device__ inline float wave_sum64(float v) {
    #pragma unroll
    for (int o = 32; o > 0; o >>= 1) v += __shfl_xor(v, o, 64);
    return v;
}

// ---------------- CSR build ----------------
__global__ void k_zero_cnt(int* __restrict__ cnt) {
    int i = blockIdx.x * blockDim.x + threadIdx.x;
    if (i < N_NODES) cnt[i] = 0;
}

__global__ void k_count(const int* __restrict__ dst, int* __restrict__ cnt) {
    int e = blockIdx.x * blockDim.x + threadIdx.x;
    if (e < N_EDGES) atomicAdd(&cnt[dst[e]], 1);
}

// stage 1: per-block exclusive scan into row_ptr, block sums into bsum; fused dinv
__global__ void k_scan1(const int* __restrict__ cnt, int* __restrict__ row_ptr,
                        int* __restrict__ bsum, float* __restrict__ dinv) {
    __shared__ int wsum[4];
    int tid = threadIdx.x, lane = tid & 63, w = tid >> 6;
    int i = blockIdx.x * 256 + tid;
    int v = (i < N_NODES) ? cnt[i] : 0;
    if (i < N_NODES) dinv[i] = rsqrtf((float)v + 1.0f);
    int isc = v;
    #pragma unroll
    for (int o = 1; o < 64; o <<= 1) {
        int n = __shfl_up(isc, o, 64);
        if (lane >= o) isc += n;
    }
    if (lane == 63) wsum[w] = isc;
    __syncthreads();
    int woff = 0;
    #pragma unroll
    for (int k = 0; k < 4; k++) woff += (k < w) ? wsum[k] : 0;
    if (i < N_NODES) row_ptr[i] = woff + isc - v;
    if (tid == 255) bsum[blockIdx.x] = woff + isc;   // block total
}

// stage 2: single block scans the 196 block sums -> exclusive boff
__global__ void k_scan2(const int* __restrict__ bsum, int* __restrict__ boff) {
    __shared__ int wsum[4];
    int tid = threadIdx.x, lane = tid & 63, w = tid >> 6;
    int v = (tid < SCAN_BLOCKS) ? bsum[tid] : 0;
    int isc = v;
    #pragma unroll
    for (int o = 1; o < 64; o <<= 1) {
        int n = __shfl_up(isc, o, 64);
        if (lane >= o) isc += n;
    }
    if (lane == 63) wsum[w] = isc;
    __syncthreads();
    int woff = 0;
    #pragma unroll
    for (int k = 0; k < 4; k++) woff += (k < w) ? wsum[k] : 0;
    if (tid < SCAN_BLOCKS) boff[tid] = woff + isc - v;
}

// stage 3: apply block offsets, init cursor, close row_ptr
__global__ void k_scan3(int* __restrict__ row_ptr, const int* __restrict__ boff,
                        int* __restrict__ cursor) {
    int i = blockIdx.x * blockDim.x + threadIdx.x;
    if (i < N_NODES) {
        int r = row_ptr[i] + boff[i >> 8];
        row_ptr[i] = r;
        cursor[i] = r;
    }
    if (i == 0) row_ptr[N_NODES] = N_EDGES;
}

__global__ void k_fill(const int* __restrict__ src, const int* __restrict__ dst,
                       const float* __restrict__ dinv, int* __restrict__ cursor,
                       int* __restrict__ col, float* __restrict__ ew,
                       int* __restrict__ dstc, int* __restrict__ perm) {
    int e = blockIdx.x * blockDim.x + threadIdx.x;
    if (e < N_EDGES) {
        int s = src[e], d = dst[e];
        int pos = atomicAdd(&cursor[d], 1);
        col[pos] = s;
        ew[pos] = dinv[s] * dinv[d];
        dstc[pos] = d;
        perm[pos] = e;
    }
}

// ---------------- out = hin @ W (+bias) : W col cached in VGPRs, x via s_load ----------------
__global__ void __launch_bounds__(256)
k_gemm_reg(const float* __restrict__ hin, const float* __restrict__ W,
           const float* __restrict__ bias, float* __restrict__ out) {
    int lane = threadIdx.x & 63;
    int wid = (blockIdx.x * blockDim.x + threadIdx.x) >> 6;
    int nwaves = (gridDim.x * blockDim.x) >> 6;
    float w[64];
    #pragma unroll
    for (int k = 0; k < 64; k++) w[k] = W[k * 64 + lane];
    float binit = bias ? bias[lane] : 0.0f;
    for (int row = wid; row < N_NODES; row += nwaves) {
        int r = __builtin_amdgcn_readfirstlane(row);
        const float* xr = hin + r * 64;
        float acc = binit;
        #pragma unroll
        for (int k = 0; k < 64; k++) acc = fmaf(xr[k], w[k], acc);
        out[r * 64 + lane] = acc;
    }
}

// fused P/Q: first half of blocks -> P = h@W1a + b1, second half -> Q = h@W1b
__global__ void __launch_bounds__(256)
k_gemm_pq(const float* __restrict__ hin, const float* __restrict__ Wp,
          const float* __restrict__ bp, const float* __restrict__ Wq,
          float* __restrict__ P, float* __restrict__ Q) {
    int half = gridDim.x >> 1;
    bool isQ = (blockIdx.x >= half);
    const float* W = isQ ? Wq : Wp;
    float* out = isQ ? Q : P;
    int lane = threadIdx.x & 63;
    int bid = isQ ? (blockIdx.x - half) : blockIdx.x;
    int wid = (bid * blockDim.x + threadIdx.x) >> 6;
    int nwaves = (half * blockDim.x) >> 6;
    float w[64];
    #pragma unroll
    for (int k = 0; k < 64; k++) w[k] = W[k * 64 + lane];
    float binit = (!isQ && bp) ? bp[lane] : 0.0f;
    for (int row = wid; row < N_NODES; row += nwaves) {
        int r = __builtin_amdgcn_readfirstlane(row);
        const float* xr = hin + r * 64;
        float acc = binit;
        #pragma unroll
        for (int k = 0; k < 64; k++) acc = fmaf(xr[k], w[k], acc);
        out[r * 64 + lane] = acc;
    }
}

// ---------------- fused: self-loop + CSR gather + LayerNorm + ReLU ----------------
// wave per node; 4 edge-slots (16 lanes each); col/ew preloaded + shfl-distributed
__global__ void __launch_bounds__(256)
k_gather_ln(const float* __restrict__ t, const float* __restrict__ dinv,
            const int* __restrict__ row_ptr, const int* __restrict__ col,
            const float* __restrict__ ew, const float* __restrict__ cb,
            const float* __restrict__ g, const float* __restrict__ b,
            float* __restrict__ h) {
    int gid = blockIdx.x * blockDim.x + threadIdx.x;
    int node = gid >> 6, lane = gid & 63;
    if (node >= N_NODES) return;
    int n0 = __builtin_amdgcn_readfirstlane(node);
    int q = lane >> 4, c4 = lane & 15;
    const float4* t4 = (const float4*)t;

    float di = dinv[n0];
    float4 acc = make_float4(0.f, 0.f, 0.f, 0.f);
    if (q == 0) {
        float4 tv = t4[(size_t)n0 * 16 + c4];
        float4 cbv = ((const float4*)cb)[c4];
        float s2 = di * di;
        acc.x = fmaf(tv.x, s2, acc.x + cbv.x);
        acc.y = fmaf(tv.y, s2, acc.y + cbv.y);
        acc.z = fmaf(tv.z, s2, acc.z + cbv.z);
        acc.w = fmaf(tv.w, s2, acc.w + cbv.w);
    }
    int beg = row_ptr[n0], end = row_ptr[n0 + 1];
    int deg = end - beg;

    // preload up to 64 edges' col/ew into one register each, lane-indexed
    int cL = 0; float wL = 0.0f;
    if (lane < deg) { cL = col[beg + lane]; wL = ew[beg + lane]; }
    int steps = (min(deg, 64) + 3) >> 2;

    #pragma unroll 4
    for (int st = 0; st < steps; st++) {
        int idx = 4 * st + q;
        int s = __shfl(cL, idx & 63, 64);          // cL=0 for masked lanes -> safe addr
        float wgt = __shfl(wL, idx & 63, 64);      // wL=0 for masked lanes -> adds 0
        float4 tv = t4[(size_t)s * 16 + c4];
        acc.x = fmaf(tv.x, wgt, acc.x);
        acc.y = fmaf(tv.y, wgt, acc.y);
        acc.z = fmaf(tv.z, wgt, acc.z);
        acc.w = fmaf(tv.w, wgt, acc.w);
    }
    // tail (deg > 64; essentially never for this graph, kept for correctness)
    for (int j = beg + 64 + q; j < end; j += 4) {
        int s = col[j];
        float wgt = ew[j];
        float4 tv = t4[(size_t)s * 16 + c4];
        acc.x = fmaf(tv.x, wgt, acc.x);
        acc.y = fmaf(tv.y, wgt, acc.y);
        acc.z = fmaf(tv.z, wgt, acc.z);
        acc.w = fmaf(tv.w, wgt, acc.w);
    }

    #pragma unroll
    for (int o = 16; o <= 32; o <<= 1) {
        acc.x += __shfl_xor(acc.x, o, 64);
        acc.y += __shfl_xor(acc.y, o, 64);
        acc.z += __shfl_xor(acc.z, o, 64);
        acc.w += __shfl_xor(acc.w, o, 64);
    }
    float ps = acc.x + acc.y + acc.z + acc.w;
    float mu = wave_sum64(ps) * (1.0f / 256.0f);
    float4 d = make_float4(acc.x - mu, acc.y - mu, acc.z - mu, acc.w - mu);
    float vps = d.x * d.x + d.y * d.y + d.z * d.z + d.w * d.w;
    float var = wave_sum64(vps) * (1.0f / 256.0f);
    float rstd = rsqrtf(var + LN_EPS);
    if (q == 0) {
        float4 gv = ((const float4*)g)[c4];
        float4 bv = ((const float4*)b)[c4];
        float4 y;
        y.x = fmaxf(fmaf(d.x * rstd, gv.x, bv.x), 0.f);
        y.y = fmaxf(fmaf(d.y * rstd, gv.y, bv.y), 0.f);
        y.z = fmaxf(fmaf(d.z * rstd, gv.z, bv.z), 0.f);
        y.w = fmaxf(fmaf(d.w * rstd, gv.w, bv.w), 0.f);
        ((float4*)h)[(size_t)n0 * 16 + c4] = y;
    }
}

// ---------------- decoder: CSR-ordered edges (dst-grouped) ----------------
// Q[dstc[pos]] is shared by ~deg consecutive threads -> broadcast; out scattered via perm.
// RULE: acc[]/acc2[] indices compile-time constant (no scratch spill).
__global__ void __launch_bounds__(256)
k_decoder(const float* __restrict__ P, const float* __restrict__ Q,
          const int* __restrict__ col, const int* __restrict__ dstc,
          const int* __restrict__ perm, const float* __restrict__ attr,
          const float* __restrict__ W1c,
          const float* __restrict__ W2, const float* __restrict__ b2,
          const float* __restrict__ W3, const float* __restrict__ b3,
          float* __restrict__ out) {
    int pos = blockIdx.x * blockDim.x + threadIdx.x;
    if (pos >= N_EDGES) return;
    int s = col[pos];
    int d = dstc[pos];
    int e = perm[pos];

    const float4* ap = (const float4*)(attr + (size_t)e * 16);
    float4 av0 = ap[0], av1 = ap[1], av2 = ap[2], av3 = ap[3];

    float acc[64];
    const float4* Pp = (const float4*)(P + (size_t)s * 64);
    const float4* Qp = (const float4*)(Q + (size_t)d * 64);
    #pragma unroll
    for (int c = 0; c < 16; c++) {
        float4 pv = Pp[c], qv = Qp[c];
        acc[4 * c + 0] = pv.x + qv.x;
        acc[4 * c + 1] = pv.y + qv.y;
        acc[4 * c + 2] = pv.z + qv.z;
        acc[4 * c + 3] = pv.w + qv.w;
    }

    #pragma unroll
    for (int j = 0; j < 64; j++) {
        float a = acc[j];
        a = fmaf(av0.x, W1c[0 * 64 + j], a);
        a = fmaf(av0.y, W1c[1 * 64 + j], a);
        a = fmaf(av0.z, W1c[2 * 64 + j], a);
        a = fmaf(av0.w, W1c[3 * 64 + j], a);
        a = fmaf(av1.x, W1c[4 * 64 + j], a);
        a = fmaf(av1.y, W1c[5 * 64 + j], a);
        a = fmaf(av1.z, W1c[6 * 64 + j], a);
        a = fmaf(av1.w, W1c[7 * 64 + j], a);
        a = fmaf(av2.x, W1c[8 * 64 + j], a);
        a = fmaf(av2.y, W1c[9 * 64 + j], a);
        a = fmaf(av2.z, W1c[10 * 64 + j], a);
        a = fmaf(av2.w, W1c[11 * 64 + j], a);
        a = fmaf(av3.x, W1c[12 * 64 + j], a);
        a = fmaf(av3.y, W1c[13 * 64 + j], a);
        a = fmaf(av3.z, W1c[14 * 64 + j], a);
        a = fmaf(av3.w, W1c[15 * 64 + j], a);
        acc[j] = fmaxf(a, 0.0f);
    }

    float acc2[32];
    #pragma unroll
    for (int j = 0; j < 32; j++) acc2[j] = b2[j];
    #pragma unroll
    for (int k = 0; k < 64; k++) {
        float hk = acc[k];
        #pragma unroll
        for (int j = 0; j < 32; j++)
            acc2[j] = fmaf(hk, W2[k * 32 + j], acc2[j]);
    }

    float o = b3[0];
    #pragma unroll
    for (int j = 0; j < 32; j++)
        o = fmaf(fmaxf(acc2[j], 0.0f), W3[j], o);
    out[e] = o;
}

// ---------------- launch ----------------
extern "C" void kernel_launch(void* const* d_in, const int* in_sizes, int n_in,
                              void* d_out, int out_size, void* d_ws, size_t ws_size,
                              hipStream_t stream) {
    const float* x      = (const float*)d_in[0];
    const int*   ei     = (const int*)d_in[1];
    const float* attr   = (const float*)d_in[2];
    const float* conv_w = (const float*)d_in[3];
    const float* conv_b = (const float*)d_in[4];
    const float* ln_g   = (const float*)d_in[5];
    const float* ln_b   = (const float*)d_in[6];
    const float* dw1    = (const float*)d_in[7];
    const float* db1    = (const float*)d_in[8];
    const float* dw2    = (const float*)d_in[9];
    const float* db2    = (const float*)d_in[10];
    const float* dw3    = (const float*)d_in[11];
    const float* db3    = (const float*)d_in[12];
    float* out = (float*)d_out;

    const int* src = ei;
    const int* dst = ei + N_EDGES;

    char* p = (char*)d_ws;
    float* dinv    = (float*)p; p += sizeof(float) * N_NODES;
    float* t       = (float*)p; p += sizeof(float) * (size_t)N_NODES * 64;
    float* h       = (float*)p; p += sizeof(float) * (size_t)N_NODES * 64;
    float* Q       = (float*)p; p += sizeof(float) * (size_t)N_NODES * 64;
    int*   cnt     = (int*)p;   p += sizeof(int) * N_NODES;
    int*   cursor  = (int*)p;   p += sizeof(int) * N_NODES;
    int*   row_ptr = (int*)p;   p += sizeof(int) * (N_NODES + 1);
    int*   col     = (int*)p;   p += sizeof(int) * N_EDGES;
    float* ew      = (float*)p; p += sizeof(float) * N_EDGES;
    int*   dstc    = (int*)p;   p += sizeof(int) * N_EDGES;
    int*   perm    = (int*)p;   p += sizeof(int) * N_EDGES;
    int*   bsum    = (int*)p;   p += sizeof(int) * 256;
    int*   boff    = (int*)p;   p += sizeof(int) * 256;

    const int nb_nodes = (N_NODES + 255) / 256;
    const int nb_edges = (N_EDGES + 255) / 256;

    k_zero_cnt<<<nb_nodes, 256, 0, stream>>>(cnt);
    k_count<<<nb_edges, 256, 0, stream>>>(dst, cnt);
    k_scan1<<<SCAN_BLOCKS, 256, 0, stream>>>(cnt, row_ptr, bsum, dinv);
    k_scan2<<<1, 256, 0, stream>>>(bsum, boff);
    k_scan3<<<nb_nodes, 256, 0, stream>>>(row_ptr, boff, cursor);
    k_fill<<<nb_edges, 256, 0, stream>>>(src, dst, dinv, cursor, col, ew, dstc, perm);

    const int gemm_blocks = 1024;
    const int gather_blocks = N_NODES / 4;

    const float* hin = x;
    for (int l = 0; l < 3; l++) {
        k_gemm_reg<<<gemm_blocks, 256, 0, stream>>>(hin, conv_w + l * 4096, nullptr, t);
        k_gather_ln<<<gather_blocks, 256, 0, stream>>>(
            t, dinv, row_ptr, col, ew, conv_b + l * 64,
            ln_g + l * 64, ln_b + l * 64, h);
        hin = h;
    }

    // P = h @ W1[0:64] + b1 (into t) ; Q = h @ W1[64:128]  — one fused dispatch
    k_gemm_pq<<<2 * gemm_blocks, 256, 0, stream>>>(h, dw1, db1, dw1 + 64 * 64, t, Q);

    k_decoder<<<nb_edges, 256, 0, stream>>>(
        t, Q, col, dstc, perm, attr, dw1 + 128 * 64, dw2, db2, dw3, db3, out);
}

// Round 6
// 485.083 us; speedup vs baseline: 2.4686x; 1.0805x over previous
//
#include <hip/hip_runtime.h>
#include <hip/hip_fp16.h>

#define N_NODES 50000
#define N_EDGES 800000
#define HID 64
#define F_EDGE 16
#define LN_EPS 1e-5f
#define SCAN_BLOCKS ((N_NODES + 255) / 256)   // 196

// ---------------- utility: 64-lane wave reduction ----------------
__device__ inline float wave_sum64(float v) {
    #pragma unroll
    for (int o = 32; o > 0; o >>= 1) v += __shfl_xor(v, o, 64);
    return v;
}

// ---------------- CSR build ----------------
__global__ void k_zero_cnt(int* __restrict__ cnt) {
    int i = blockIdx.x * blockDim.x + threadIdx.x;
    if (i < N_NODES) cnt[i] = 0;
}

__global__ void k_count(const int* __restrict__ dst, int* __restrict__ cnt) {
    int e = blockIdx.x * blockDim.x + threadIdx.x;
    if (e < N_EDGES) atomicAdd(&cnt[dst[e]], 1);
}

// stage 1: per-block exclusive scan into row_ptr, block sums into bsum; fused dinv
__global__ void k_scan1(const int* __restrict__ cnt, int* __restrict__ row_ptr,
                        int* __restrict__ bsum, float* __restrict__ dinv) {
    __shared__ int wsum[4];
    int tid = threadIdx.x, lane = tid & 63, w = tid >> 6;
    int i = blockIdx.x * 256 + tid;
    int v = (i < N_NODES) ? cnt[i] : 0;
    if (i < N_NODES) dinv[i] = rsqrtf((float)v + 1.0f);
    int isc = v;
    #pragma unroll
    for (int o = 1; o < 64; o <<= 1) {
        int n = __shfl_up(isc, o, 64);
        if (lane >= o) isc += n;
    }
    if (lane == 63) wsum[w] = isc;
    __syncthreads();
    int woff = 0;
    #pragma unroll
    for (int k = 0; k < 4; k++) woff += (k < w) ? wsum[k] : 0;
    if (i < N_NODES) row_ptr[i] = woff + isc - v;
    if (tid == 255) bsum[blockIdx.x] = woff + isc;
}

// stage 2: single block scans the block sums -> exclusive boff
__global__ void k_scan2(const int* __restrict__ bsum, int* __restrict__ boff) {
    __shared__ int wsum[4];
    int tid = threadIdx.x, lane = tid & 63, w = tid >> 6;
    int v = (tid < SCAN_BLOCKS) ? bsum[tid] : 0;
    int isc = v;
    #pragma unroll
    for (int o = 1; o < 64; o <<= 1) {
        int n = __shfl_up(isc, o, 64);
        if (lane >= o) isc += n;
    }
    if (lane == 63) wsum[w] = isc;
    __syncthreads();
    int woff = 0;
    #pragma unroll
    for (int k = 0; k < 4; k++) woff += (k < w) ? wsum[k] : 0;
    if (tid < SCAN_BLOCKS) boff[tid] = woff + isc - v;
}

// stage 3: apply block offsets, init cursor
__global__ void k_scan3(int* __restrict__ row_ptr, const int* __restrict__ boff,
                        int* __restrict__ cursor) {
    int i = blockIdx.x * blockDim.x + threadIdx.x;
    if (i < N_NODES) {
        int r = row_ptr[i] + boff[i >> 8];
        row_ptr[i] = r;
        cursor[i] = r;
    }
    if (i == 0) row_ptr[N_NODES] = N_EDGES;
}

__global__ void k_fill(const int* __restrict__ src, const int* __restrict__ dst,
                       const float* __restrict__ dinv, int* __restrict__ cursor,
                       int* __restrict__ col, float* __restrict__ ew) {
    int e = blockIdx.x * blockDim.x + threadIdx.x;
    if (e < N_EDGES) {
        int s = src[e], d = dst[e];
        int pos = atomicAdd(&cursor[d], 1);
        col[pos] = s;
        ew[pos] = dinv[s] * dinv[d];
    }
}

// ---------------- t_h = fp16(hin @ W) : W col in VGPRs, x via s_load ----------------
__global__ void __launch_bounds__(256)
k_gemm_reg(const float* __restrict__ hin, const float* __restrict__ W,
           __half* __restrict__ out) {
    int lane = threadIdx.x & 63;
    int wid = (blockIdx.x * blockDim.x + threadIdx.x) >> 6;
    int nwaves = (gridDim.x * blockDim.x) >> 6;
    float w[64];
    #pragma unroll
    for (int k = 0; k < 64; k++) w[k] = W[k * 64 + lane];
    for (int row = wid; row < N_NODES; row += nwaves) {
        int r = __builtin_amdgcn_readfirstlane(row);
        const float* xr = hin + r * 64;
        float acc = 0.0f;
        #pragma unroll
        for (int k = 0; k < 64; k++) acc = fmaf(xr[k], w[k], acc);
        out[r * 64 + lane] = __float2half_rn(acc);
    }
}

// fused P/Q (fp16 out): first half of blocks -> P = h@W1a + b1, second half -> Q = h@W1b
__global__ void __launch_bounds__(256)
k_gemm_pq(const float* __restrict__ hin, const float* __restrict__ Wp,
          const float* __restrict__ bp, const float* __restrict__ Wq,
          __half* __restrict__ P, __half* __restrict__ Q) {
    int half_g = gridDim.x >> 1;
    bool isQ = (blockIdx.x >= half_g);
    const float* W = isQ ? Wq : Wp;
    __half* out = isQ ? Q : P;
    int lane = threadIdx.x & 63;
    int bid = isQ ? (blockIdx.x - half_g) : blockIdx.x;
    int wid = (bid * blockDim.x + threadIdx.x) >> 6;
    int nwaves = (half_g * blockDim.x) >> 6;
    float w[64];
    #pragma unroll
    for (int k = 0; k < 64; k++) w[k] = W[k * 64 + lane];
    float binit = isQ ? 0.0f : bp[lane];
    for (int row = wid; row < N_NODES; row += nwaves) {
        int r = __builtin_amdgcn_readfirstlane(row);
        const float* xr = hin + r * 64;
        float acc = binit;
        #pragma unroll
        for (int k = 0; k < 64; k++) acc = fmaf(xr[k], w[k], acc);
        out[r * 64 + lane] = __float2half_rn(acc);
    }
}

// ---------------- fused: self-loop + CSR gather (fp16 t) + LayerNorm + ReLU ----------------
// wave per node; 4 edge-slots (16 lanes each); col/ew preloaded + shfl-distributed
__global__ void __launch_bounds__(256)
k_gather_ln(const __half* __restrict__ t, const float* __restrict__ dinv,
            const int* __restrict__ row_ptr, const int* __restrict__ col,
            const float* __restrict__ ew, const float* __restrict__ cb,
            const float* __restrict__ g, const float* __restrict__ b,
            float* __restrict__ h) {
    int gid = blockIdx.x * blockDim.x + threadIdx.x;
    int node = gid >> 6, lane = gid & 63;
    if (node >= N_NODES) return;
    int n0 = __builtin_amdgcn_readfirstlane(node);
    int q = lane >> 4, c4 = lane & 15;
    const float2* t2 = (const float2*)t;   // 8 B = 4 halves per lane slot

    float di = dinv[n0];
    float4 acc = make_float4(0.f, 0.f, 0.f, 0.f);
    if (q == 0) {
        float2 raw = t2[(size_t)n0 * 16 + c4];
        const __half2* hp = (const __half2*)&raw;
        float2 f01 = __half22float2(hp[0]);
        float2 f23 = __half22float2(hp[1]);
        float4 cbv = ((const float4*)cb)[c4];
        float s2 = di * di;
        acc.x = fmaf(f01.x, s2, cbv.x);
        acc.y = fmaf(f01.y, s2, cbv.y);
        acc.z = fmaf(f23.x, s2, cbv.z);
        acc.w = fmaf(f23.y, s2, cbv.w);
    }
    int beg = row_ptr[n0], end = row_ptr[n0 + 1];
    int deg = end - beg;

    int cL = 0; float wL = 0.0f;
    if (lane < deg) { cL = col[beg + lane]; wL = ew[beg + lane]; }
    int steps = (min(deg, 64) + 3) >> 2;

    #pragma unroll 4
    for (int st = 0; st < steps; st++) {
        int idx = 4 * st + q;
        int s = __shfl(cL, idx & 63, 64);
        float wgt = __shfl(wL, idx & 63, 64);
        float2 raw = t2[(size_t)s * 16 + c4];
        const __half2* hp = (const __half2*)&raw;
        float2 f01 = __half22float2(hp[0]);
        float2 f23 = __half22float2(hp[1]);
        acc.x = fmaf(f01.x, wgt, acc.x);
        acc.y = fmaf(f01.y, wgt, acc.y);
        acc.z = fmaf(f23.x, wgt, acc.z);
        acc.w = fmaf(f23.y, wgt, acc.w);
    }
    for (int j = beg + 64 + q; j < end; j += 4) {   // deg>64 tail (rare)
        int s = col[j];
        float wgt = ew[j];
        float2 raw = t2[(size_t)s * 16 + c4];
        const __half2* hp = (const __half2*)&raw;
        float2 f01 = __half22float2(hp[0]);
        float2 f23 = __half22float2(hp[1]);
        acc.x = fmaf(f01.x, wgt, acc.x);
        acc.y = fmaf(f01.y, wgt, acc.y);
        acc.z = fmaf(f23.x, wgt, acc.z);
        acc.w = fmaf(f23.y, wgt, acc.w);
    }

    #pragma unroll
    for (int o = 16; o <= 32; o <<= 1) {
        acc.x += __shfl_xor(acc.x, o, 64);
        acc.y += __shfl_xor(acc.y, o, 64);
        acc.z += __shfl_xor(acc.z, o, 64);
        acc.w += __shfl_xor(acc.w, o, 64);
    }
    float ps = acc.x + acc.y + acc.z + acc.w;
    float mu = wave_sum64(ps) * (1.0f / 256.0f);
    float4 d = make_float4(acc.x - mu, acc.y - mu, acc.z - mu, acc.w - mu);
    float vps = d.x * d.x + d.y * d.y + d.z * d.z + d.w * d.w;
    float var = wave_sum64(vps) * (1.0f / 256.0f);
    float rstd = rsqrtf(var + LN_EPS);
    if (q == 0) {
        float4 gv = ((const float4*)g)[c4];
        float4 bv = ((const float4*)b)[c4];
        float4 y;
        y.x = fmaxf(fmaf(d.x * rstd, gv.x, bv.x), 0.f);
        y.y = fmaxf(fmaf(d.y * rstd, gv.y, bv.y), 0.f);
        y.z = fmaxf(fmaf(d.z * rstd, gv.z, bv.z), 0.f);
        y.w = fmaxf(fmaf(d.w * rstd, gv.w, bv.w), 0.f);
        ((float4*)h)[(size_t)n0 * 16 + c4] = y;
    }
}

// ---------------- decoder: original edge order, fp16 P/Q gathers ----------------
// RULE: acc[]/acc2[] indices compile-time constant (no scratch spill).
__global__ void __launch_bounds__(256)
k_decoder(const __half* __restrict__ P, const __half* __restrict__ Q,
          const int* __restrict__ src, const int* __restrict__ dst,
          const float* __restrict__ attr,
          const float* __restrict__ W1c,
          const float* __restrict__ W2, const float* __restrict__ b2,
          const float* __restrict__ W3, const float* __restrict__ b3,
          float* __restrict__ out) {
    int e = blockIdx.x * blockDim.x + threadIdx.x;
    if (e >= N_EDGES) return;
    int s = src[e], d = dst[e];

    const float4* ap = (const float4*)(attr + (size_t)e * 16);
    float4 av0 = ap[0], av1 = ap[1], av2 = ap[2], av3 = ap[3];

    // acc = P[s] + Q[d] (fp16 rows, 128 B each: 8 x float4)
    float acc[64];
    const float4* Pp = (const float4*)(P + (size_t)s * 64);
    const float4* Qp = (const float4*)(Q + (size_t)d * 64);
    #pragma unroll
    for (int c = 0; c < 8; c++) {
        float4 pv = Pp[c], qv = Qp[c];
        const __half2* ph = (const __half2*)&pv;
        const __half2* qh = (const __half2*)&qv;
        #pragma unroll
        for (int u = 0; u < 4; u++) {
            float2 pf = __half22float2(ph[u]);
            float2 qf = __half22float2(qh[u]);
            acc[8 * c + 2 * u]     = pf.x + qf.x;
            acc[8 * c + 2 * u + 1] = pf.y + qf.y;
        }
    }

    // + attr @ W1c (16x64); W1c reads wave-uniform -> scalar loads
    #pragma unroll
    for (int j = 0; j < 64; j++) {
        float a = acc[j];
        a = fmaf(av0.x, W1c[0 * 64 + j], a);
        a = fmaf(av0.y, W1c[1 * 64 + j], a);
        a = fmaf(av0.z, W1c[2 * 64 + j], a);
        a = fmaf(av0.w, W1c[3 * 64 + j], a);
        a = fmaf(av1.x, W1c[4 * 64 + j], a);
        a = fmaf(av1.y, W1c[5 * 64 + j], a);
        a = fmaf(av1.z, W1c[6 * 64 + j], a);
        a = fmaf(av1.w, W1c[7 * 64 + j], a);
        a = fmaf(av2.x, W1c[8 * 64 + j], a);
        a = fmaf(av2.y, W1c[9 * 64 + j], a);
        a = fmaf(av2.z, W1c[10 * 64 + j], a);
        a = fmaf(av2.w, W1c[11 * 64 + j], a);
        a = fmaf(av3.x, W1c[12 * 64 + j], a);
        a = fmaf(av3.y, W1c[13 * 64 + j], a);
        a = fmaf(av3.z, W1c[14 * 64 + j], a);
        a = fmaf(av3.w, W1c[15 * 64 + j], a);
        acc[j] = fmaxf(a, 0.0f);
    }

    float acc2[32];
    #pragma unroll
    for (int j = 0; j < 32; j++) acc2[j] = b2[j];
    #pragma unroll
    for (int k = 0; k < 64; k++) {
        float hk = acc[k];
        #pragma unroll
        for (int j = 0; j < 32; j++)
            acc2[j] = fmaf(hk, W2[k * 32 + j], acc2[j]);
    }

    float o = b3[0];
    #pragma unroll
    for (int j = 0; j < 32; j++)
        o = fmaf(fmaxf(acc2[j], 0.0f), W3[j], o);
    out[e] = o;
}

// ---------------- launch ----------------
extern "C" void kernel_launch(void* const* d_in, const int* in_sizes, int n_in,
                              void* d_out, int out_size, void* d_ws, size_t ws_size,
                              hipStream_t stream) {
    const float* x      = (const float*)d_in[0];
    const int*   ei     = (const int*)d_in[1];
    const float* attr   = (const float*)d_in[2];
    const float* conv_w = (const float*)d_in[3];
    const float* conv_b = (const float*)d_in[4];
    const float* ln_g   = (const float*)d_in[5];
    const float* ln_b   = (const float*)d_in[6];
    const float* dw1    = (const float*)d_in[7];
    const float* db1    = (const float*)d_in[8];
    const float* dw2    = (const float*)d_in[9];
    const float* db2    = (const float*)d_in[10];
    const float* dw3    = (const float*)d_in[11];
    const float* db3    = (const float*)d_in[12];
    float* out = (float*)d_out;

    const int* src = ei;
    const int* dst = ei + N_EDGES;

    char* p = (char*)d_ws;
    float*  dinv    = (float*)p;  p += sizeof(float) * N_NODES;
    float*  h       = (float*)p;  p += sizeof(float) * (size_t)N_NODES * 64;
    __half* t_h     = (__half*)p; p += sizeof(__half) * (size_t)N_NODES * 64;
    __half* P_h     = (__half*)p; p += sizeof(__half) * (size_t)N_NODES * 64;
    __half* Q_h     = (__half*)p; p += sizeof(__half) * (size_t)N_NODES * 64;
    int*    cnt     = (int*)p;    p += sizeof(int) * N_NODES;
    int*    cursor  = (int*)p;    p += sizeof(int) * N_NODES;
    int*    row_ptr = (int*)p;    p += sizeof(int) * (N_NODES + 1);
    int*    col     = (int*)p;    p += sizeof(int) * N_EDGES;
    float*  ew      = (float*)p;  p += sizeof(float) * N_EDGES;
    int*    bsum    = (int*)p;    p += sizeof(int) * 256;
    int*    boff    = (int*)p;    p += sizeof(int) * 256;

    const int nb_nodes = (N_NODES + 255) / 256;
    const int nb_edges = (N_EDGES + 255) / 256;

    k_zero_cnt<<<nb_nodes, 256, 0, stream>>>(cnt);
    k_count<<<nb_edges, 256, 0, stream>>>(dst, cnt);
    k_scan1<<<SCAN_BLOCKS, 256, 0, stream>>>(cnt, row_ptr, bsum, dinv);
    k_scan2<<<1, 256, 0, stream>>>(bsum, boff);
    k_scan3<<<nb_nodes, 256, 0, stream>>>(row_ptr, boff, cursor);
    k_fill<<<nb_edges, 256, 0, stream>>>(src, dst, dinv, cursor, col, ew);

    const int gemm_blocks = 1024;
    const int gather_blocks = N_NODES / 4;

    const float* hin = x;
    for (int l = 0; l < 3; l++) {
        k_gemm_reg<<<gemm_blocks, 256, 0, stream>>>(hin, conv_w + l * 4096, t_h);
        k_gather_ln<<<gather_blocks, 256, 0, stream>>>(
            t_h, dinv, row_ptr, col, ew, conv_b + l * 64,
            ln_g + l * 64, ln_b + l * 64, h);
        hin = h;
    }

    // P = h @ W1[0:64] + b1 ; Q = h @ W1[64:128]  (fp16 outputs, one dispatch)
    k_gemm_pq<<<2 * gemm_blocks, 256, 0, stream>>>(h, dw1, db1, dw1 + 64 * 64, P_h, Q_h);

    k_decoder<<<nb_edges, 256, 0, stream>>>(
        P_h, Q_h, src, dst, attr, dw1 + 128 * 64, dw2, db2, dw3, db3, out);
}

// Round 7
// 476.906 us; speedup vs baseline: 2.5109x; 1.0171x over previous
//
#include <hip/hip_runtime.h>
#include <hip/hip_fp16.h>

#define N_NODES 50000
#define N_EDGES 800000
#define HID 64
#define F_EDGE 16
#define LN_EPS 1e-5f
#define SCAN_BLOCKS ((N_NODES + 255) / 256)   // 196

// ---------------- utility: 64-lane wave reduction ----------------
__device__ inline float wave_sum64(float v) {
    #pragma unroll
    for (int o = 32; o > 0; o >>= 1) v += __shfl_xor(v, o, 64);
    return v;
}

// ---------------- CSR build ----------------
__global__ void k_zero_cnt(int* __restrict__ cnt) {
    int i = blockIdx.x * blockDim.x + threadIdx.x;
    if (i < N_NODES) cnt[i] = 0;
}

__global__ void k_count(const int* __restrict__ dst, int* __restrict__ cnt) {
    int e = blockIdx.x * blockDim.x + threadIdx.x;
    if (e < N_EDGES) atomicAdd(&cnt[dst[e]], 1);
}

// stage 1: per-block exclusive scan into row_ptr, block sums into bsum; fused dinv
__global__ void k_scan1(const int* __restrict__ cnt, int* __restrict__ row_ptr,
                        int* __restrict__ bsum, float* __restrict__ dinv) {
    __shared__ int wsum[4];
    int tid = threadIdx.x, lane = tid & 63, w = tid >> 6;
    int i = blockIdx.x * 256 + tid;
    int v = (i < N_NODES) ? cnt[i] : 0;
    if (i < N_NODES) dinv[i] = rsqrtf((float)v + 1.0f);
    int isc = v;
    #pragma unroll
    for (int o = 1; o < 64; o <<= 1) {
        int n = __shfl_up(isc, o, 64);
        if (lane >= o) isc += n;
    }
    if (lane == 63) wsum[w] = isc;
    __syncthreads();
    int woff = 0;
    #pragma unroll
    for (int k = 0; k < 4; k++) woff += (k < w) ? wsum[k] : 0;
    if (i < N_NODES) row_ptr[i] = woff + isc - v;
    if (tid == 255) bsum[blockIdx.x] = woff + isc;
}

// stage 2: single block scans the block sums -> exclusive boff
__global__ void k_scan2(const int* __restrict__ bsum, int* __restrict__ boff) {
    __shared__ int wsum[4];
    int tid = threadIdx.x, lane = tid & 63, w = tid >> 6;
    int v = (tid < SCAN_BLOCKS) ? bsum[tid] : 0;
    int isc = v;
    #pragma unroll
    for (int o = 1; o < 64; o <<= 1) {
        int n = __shfl_up(isc, o, 64);
        if (lane >= o) isc += n;
    }
    if (lane == 63) wsum[w] = isc;
    __syncthreads();
    int woff = 0;
    #pragma unroll
    for (int k = 0; k < 4; k++) woff += (k < w) ? wsum[k] : 0;
    if (tid < SCAN_BLOCKS) boff[tid] = woff + isc - v;
}

// stage 3: apply block offsets, init cursor
__global__ void k_scan3(int* __restrict__ row_ptr, const int* __restrict__ boff,
                        int* __restrict__ cursor) {
    int i = blockIdx.x * blockDim.x + threadIdx.x;
    if (i < N_NODES) {
        int r = row_ptr[i] + boff[i >> 8];
        row_ptr[i] = r;
        cursor[i] = r;
    }
    if (i == 0) row_ptr[N_NODES] = N_EDGES;
}

__global__ void k_fill(const int* __restrict__ src, const int* __restrict__ dst,
                       const float* __restrict__ dinv, int* __restrict__ cursor,
                       int* __restrict__ col, float* __restrict__ ew) {
    int e = blockIdx.x * blockDim.x + threadIdx.x;
    if (e < N_EDGES) {
        int s = src[e], d = dst[e];
        int pos = atomicAdd(&cursor[d], 1);
        col[pos] = s;
        ew[pos] = dinv[s] * dinv[d];
    }
}

// ---------------- t_h = fp16(hin @ W) : W col in VGPRs, x via s_load ----------------
__global__ void __launch_bounds__(256)
k_gemm_reg(const float* __restrict__ hin, const float* __restrict__ W,
           __half* __restrict__ out) {
    int lane = threadIdx.x & 63;
    int wid = (blockIdx.x * blockDim.x + threadIdx.x) >> 6;
    int nwaves = (gridDim.x * blockDim.x) >> 6;
    float w[64];
    #pragma unroll
    for (int k = 0; k < 64; k++) w[k] = W[k * 64 + lane];
    for (int row = wid; row < N_NODES; row += nwaves) {
        int r = __builtin_amdgcn_readfirstlane(row);
        const float* xr = hin + r * 64;
        float acc = 0.0f;
        #pragma unroll
        for (int k = 0; k < 64; k++) acc = fmaf(xr[k], w[k], acc);
        out[r * 64 + lane] = __float2half_rn(acc);
    }
}

// fused P/Q (fp16 out): first half of blocks -> P = h@W1a + b1, second half -> Q = h@W1b
__global__ void __launch_bounds__(256)
k_gemm_pq(const float* __restrict__ hin, const float* __restrict__ Wp,
          const float* __restrict__ bp, const float* __restrict__ Wq,
          __half* __restrict__ P, __half* __restrict__ Q) {
    int half_g = gridDim.x >> 1;
    bool isQ = (blockIdx.x >= half_g);
    const float* W = isQ ? Wq : Wp;
    __half* out = isQ ? Q : P;
    int lane = threadIdx.x & 63;
    int bid = isQ ? (blockIdx.x - half_g) : blockIdx.x;
    int wid = (bid * blockDim.x + threadIdx.x) >> 6;
    int nwaves = (half_g * blockDim.x) >> 6;
    float w[64];
    #pragma unroll
    for (int k = 0; k < 64; k++) w[k] = W[k * 64 + lane];
    float binit = isQ ? 0.0f : bp[lane];
    for (int row = wid; row < N_NODES; row += nwaves) {
        int r = __builtin_amdgcn_readfirstlane(row);
        const float* xr = hin + r * 64;
        float acc = binit;
        #pragma unroll
        for (int k = 0; k < 64; k++) acc = fmaf(xr[k], w[k], acc);
        out[r * 64 + lane] = __float2half_rn(acc);
    }
}

// ---------------- fused: self-loop + CSR gather (fp16 t) + LayerNorm + ReLU ----------------
// wave per node; 8 edge-slots x 8 lanes x 16 B (float4 = 8 halves) per gather instr.
__global__ void __launch_bounds__(256)
k_gather_ln(const __half* __restrict__ t, const float* __restrict__ dinv,
            const int* __restrict__ row_ptr, const int* __restrict__ col,
            const float* __restrict__ ew, const float* __restrict__ cb,
            const float* __restrict__ g, const float* __restrict__ b,
            float* __restrict__ h) {
    int gid = blockIdx.x * blockDim.x + threadIdx.x;
    int node = gid >> 6, lane = gid & 63;
    if (node >= N_NODES) return;
    int n0 = __builtin_amdgcn_readfirstlane(node);
    int q = lane >> 3;        // edge slot 0..7
    int c8 = lane & 7;        // channel-octet 0..7 (channels 8*c8..8*c8+7)
    const float4* t4 = (const float4*)t;    // 16 B = 8 halves per element

    float acc[8];
    #pragma unroll
    for (int u = 0; u < 8; u++) acc[u] = 0.0f;

    // self-loop + bias on slot 0
    if (q == 0) {
        float di = dinv[n0];
        float s2 = di * di;
        float4 raw = t4[(size_t)n0 * 8 + c8];
        const __half2* hp = (const __half2*)&raw;
        const float4* cb4 = (const float4*)cb;   // channels 8*c8.. as 2 float4
        float4 cb0 = cb4[2 * c8], cb1 = cb4[2 * c8 + 1];
        float2 f0 = __half22float2(hp[0]);
        float2 f1 = __half22float2(hp[1]);
        float2 f2 = __half22float2(hp[2]);
        float2 f3 = __half22float2(hp[3]);
        acc[0] = fmaf(f0.x, s2, cb0.x); acc[1] = fmaf(f0.y, s2, cb0.y);
        acc[2] = fmaf(f1.x, s2, cb0.z); acc[3] = fmaf(f1.y, s2, cb0.w);
        acc[4] = fmaf(f2.x, s2, cb1.x); acc[5] = fmaf(f2.y, s2, cb1.y);
        acc[6] = fmaf(f3.x, s2, cb1.z); acc[7] = fmaf(f3.y, s2, cb1.w);
    }

    int beg = row_ptr[n0], end = row_ptr[n0 + 1];
    int deg = end - beg;

    // preload up to 64 edges' col/ew, lane-indexed
    int cL = 0; float wL = 0.0f;
    if (lane < deg) { cL = col[beg + lane]; wL = ew[beg + lane]; }
    int steps = (min(deg, 64) + 7) >> 3;

    #pragma unroll 4
    for (int st = 0; st < steps; st++) {
        int idx = 8 * st + q;                  // <= 63
        int s = __shfl(cL, idx, 64);           // 0 for masked lanes -> safe addr
        float wgt = __shfl(wL, idx, 64);       // 0 for masked lanes -> adds 0
        float4 raw = t4[(size_t)s * 8 + c8];
        const __half2* hp = (const __half2*)&raw;
        float2 f0 = __half22float2(hp[0]);
        float2 f1 = __half22float2(hp[1]);
        float2 f2 = __half22float2(hp[2]);
        float2 f3 = __half22float2(hp[3]);
        acc[0] = fmaf(f0.x, wgt, acc[0]); acc[1] = fmaf(f0.y, wgt, acc[1]);
        acc[2] = fmaf(f1.x, wgt, acc[2]); acc[3] = fmaf(f1.y, wgt, acc[3]);
        acc[4] = fmaf(f2.x, wgt, acc[4]); acc[5] = fmaf(f2.y, wgt, acc[5]);
        acc[6] = fmaf(f3.x, wgt, acc[6]); acc[7] = fmaf(f3.y, wgt, acc[7]);
    }
    // tail deg>64 (essentially never; kept for correctness): all 8 lanes of slot q do row col[j]
    for (int j = beg + 64 + q; j < end; j += 8) {
        int s = col[j];
        float wgt = ew[j];
        float4 raw = t4[(size_t)s * 8 + c8];
        const __half2* hp = (const __half2*)&raw;
        float2 f0 = __half22float2(hp[0]);
        float2 f1 = __half22float2(hp[1]);
        float2 f2 = __half22float2(hp[2]);
        float2 f3 = __half22float2(hp[3]);
        acc[0] = fmaf(f0.x, wgt, acc[0]); acc[1] = fmaf(f0.y, wgt, acc[1]);
        acc[2] = fmaf(f1.x, wgt, acc[2]); acc[3] = fmaf(f1.y, wgt, acc[3]);
        acc[4] = fmaf(f2.x, wgt, acc[4]); acc[5] = fmaf(f2.y, wgt, acc[5]);
        acc[6] = fmaf(f3.x, wgt, acc[6]); acc[7] = fmaf(f3.y, wgt, acc[7]);
    }

    // reduce across the 8 slots (lane bits 3,4,5)
    #pragma unroll
    for (int o = 8; o <= 32; o <<= 1) {
        #pragma unroll
        for (int u = 0; u < 8; u++) acc[u] += __shfl_xor(acc[u], o, 64);
    }

    // LayerNorm: each channel replicated 8x across wave -> divisor 512
    float ps = 0.0f;
    #pragma unroll
    for (int u = 0; u < 8; u++) ps += acc[u];
    float mu = wave_sum64(ps) * (1.0f / 512.0f);
    float dd[8], vps = 0.0f;
    #pragma unroll
    for (int u = 0; u < 8; u++) { dd[u] = acc[u] - mu; vps += dd[u] * dd[u]; }
    float var = wave_sum64(vps) * (1.0f / 512.0f);
    float rstd = rsqrtf(var + LN_EPS);

    if (q == 0) {
        const float4* g4 = (const float4*)g;
        const float4* b4 = (const float4*)b;
        float4 g0 = g4[2 * c8], g1 = g4[2 * c8 + 1];
        float4 b0 = b4[2 * c8], b1v = b4[2 * c8 + 1];
        float4 y0, y1;
        y0.x = fmaxf(fmaf(dd[0] * rstd, g0.x, b0.x), 0.f);
        y0.y = fmaxf(fmaf(dd[1] * rstd, g0.y, b0.y), 0.f);
        y0.z = fmaxf(fmaf(dd[2] * rstd, g0.z, b0.z), 0.f);
        y0.w = fmaxf(fmaf(dd[3] * rstd, g0.w, b0.w), 0.f);
        y1.x = fmaxf(fmaf(dd[4] * rstd, g1.x, b1v.x), 0.f);
        y1.y = fmaxf(fmaf(dd[5] * rstd, g1.y, b1v.y), 0.f);
        y1.z = fmaxf(fmaf(dd[6] * rstd, g1.z, b1v.z), 0.f);
        y1.w = fmaxf(fmaf(dd[7] * rstd, g1.w, b1v.w), 0.f);
        float4* h4 = (float4*)h;
        h4[(size_t)n0 * 16 + 2 * c8] = y0;
        h4[(size_t)n0 * 16 + 2 * c8 + 1] = y1;
    }
}

// ---------------- decoder: original edge order, fp16 P/Q gathers ----------------
// RULE: acc[]/acc2[] indices compile-time constant (no scratch spill).
__global__ void __launch_bounds__(256)
k_decoder(const __half* __restrict__ P, const __half* __restrict__ Q,
          const int* __restrict__ src, const int* __restrict__ dst,
          const float* __restrict__ attr,
          const float* __restrict__ W1c,
          const float* __restrict__ W2, const float* __restrict__ b2,
          const float* __restrict__ W3, const float* __restrict__ b3,
          float* __restrict__ out) {
    int e = blockIdx.x * blockDim.x + threadIdx.x;
    if (e >= N_EDGES) return;
    int s = src[e], d = dst[e];

    const float4* ap = (const float4*)(attr + (size_t)e * 16);
    float4 av0 = ap[0], av1 = ap[1], av2 = ap[2], av3 = ap[3];

    // acc = P[s] + Q[d] (fp16 rows, 128 B each: 8 x float4)
    float acc[64];
    const float4* Pp = (const float4*)(P + (size_t)s * 64);
    const float4* Qp = (const float4*)(Q + (size_t)d * 64);
    #pragma unroll
    for (int c = 0; c < 8; c++) {
        float4 pv = Pp[c], qv = Qp[c];
        const __half2* ph = (const __half2*)&pv;
        const __half2* qh = (const __half2*)&qv;
        #pragma unroll
        for (int u = 0; u < 4; u++) {
            float2 pf = __half22float2(ph[u]);
            float2 qf = __half22float2(qh[u]);
            acc[8 * c + 2 * u]     = pf.x + qf.x;
            acc[8 * c + 2 * u + 1] = pf.y + qf.y;
        }
    }

    // + attr @ W1c (16x64); W1c reads wave-uniform -> scalar loads
    #pragma unroll
    for (int j = 0; j < 64; j++) {
        float a = acc[j];
        a = fmaf(av0.x, W1c[0 * 64 + j], a);
        a = fmaf(av0.y, W1c[1 * 64 + j], a);
        a = fmaf(av0.z, W1c[2 * 64 + j], a);
        a = fmaf(av0.w, W1c[3 * 64 + j], a);
        a = fmaf(av1.x, W1c[4 * 64 + j], a);
        a = fmaf(av1.y, W1c[5 * 64 + j], a);
        a = fmaf(av1.z, W1c[6 * 64 + j], a);
        a = fmaf(av1.w, W1c[7 * 64 + j], a);
        a = fmaf(av2.x, W1c[8 * 64 + j], a);
        a = fmaf(av2.y, W1c[9 * 64 + j], a);
        a = fmaf(av2.z, W1c[10 * 64 + j], a);
        a = fmaf(av2.w, W1c[11 * 64 + j], a);
        a = fmaf(av3.x, W1c[12 * 64 + j], a);
        a = fmaf(av3.y, W1c[13 * 64 + j], a);
        a = fmaf(av3.z, W1c[14 * 64 + j], a);
        a = fmaf(av3.w, W1c[15 * 64 + j], a);
        acc[j] = fmaxf(a, 0.0f);
    }

    float acc2[32];
    #pragma unroll
    for (int j = 0; j < 32; j++) acc2[j] = b2[j];
    #pragma unroll
    for (int k = 0; k < 64; k++) {
        float hk = acc[k];
        #pragma unroll
        for (int j = 0; j < 32; j++)
            acc2[j] = fmaf(hk, W2[k * 32 + j], acc2[j]);
    }

    float o = b3[0];
    #pragma unroll
    for (int j = 0; j < 32; j++)
        o = fmaf(fmaxf(acc2[j], 0.0f), W3[j], o);
    out[e] = o;
}

// ---------------- launch ----------------
extern "C" void kernel_launch(void* const* d_in, const int* in_sizes, int n_in,
                              void* d_out, int out_size, void* d_ws, size_t ws_size,
                              hipStream_t stream) {
    const float* x      = (const float*)d_in[0];
    const int*   ei     = (const int*)d_in[1];
    const float* attr   = (const float*)d_in[2];
    const float* conv_w = (const float*)d_in[3];
    const float* conv_b = (const float*)d_in[4];
    const float* ln_g   = (const float*)d_in[5];
    const float* ln_b   = (const float*)d_in[6];
    const float* dw1    = (const float*)d_in[7];
    const float* db1    = (const float*)d_in[8];
    const float* dw2    = (const float*)d_in[9];
    const float* db2    = (const float*)d_in[10];
    const float* dw3    = (const float*)d_in[11];
    const float* db3    = (const float*)d_in[12];
    float* out = (float*)d_out;

    const int* src = ei;
    const int* dst = ei + N_EDGES;

    char* p = (char*)d_ws;
    float*  dinv    = (float*)p;  p += sizeof(float) * N_NODES;
    float*  h       = (float*)p;  p += sizeof(float) * (size_t)N_NODES * 64;
    __half* t_h     = (__half*)p; p += sizeof(__half) * (size_t)N_NODES * 64;
    __half* P_h     = (__half*)p; p += sizeof(__half) * (size_t)N_NODES * 64;
    __half* Q_h     = (__half*)p; p += sizeof(__half) * (size_t)N_NODES * 64;
    int*    cnt     = (int*)p;    p += sizeof(int) * N_NODES;
    int*    cursor  = (int*)p;    p += sizeof(int) * N_NODES;
    int*    row_ptr = (int*)p;    p += sizeof(int) * (N_NODES + 1);
    int*    col     = (int*)p;    p += sizeof(int) * N_EDGES;
    float*  ew      = (float*)p;  p += sizeof(float) * N_EDGES;
    int*    bsum    = (int*)p;    p += sizeof(int) * 256;
    int*    boff    = (int*)p;    p += sizeof(int) * 256;

    const int nb_nodes = (N_NODES + 255) / 256;
    const int nb_edges = (N_EDGES + 255) / 256;

    k_zero_cnt<<<nb_nodes, 256, 0, stream>>>(cnt);
    k_count<<<nb_edges, 256, 0, stream>>>(dst, cnt);
    k_scan1<<<SCAN_BLOCKS, 256, 0, stream>>>(cnt, row_ptr, bsum, dinv);
    k_scan2<<<1, 256, 0, stream>>>(bsum, boff);
    k_scan3<<<nb_nodes, 256, 0, stream>>>(row_ptr, boff, cursor);
    k_fill<<<nb_edges, 256, 0, stream>>>(src, dst, dinv, cursor, col, ew);

    const int gemm_blocks = 1024;
    const int gather_blocks = N_NODES / 4;

    const float* hin = x;
    for (int l = 0; l < 3; l++) {
        k_gemm_reg<<<gemm_blocks, 256, 0, stream>>>(hin, conv_w + l * 4096, t_h);
        k_gather_ln<<<gather_blocks, 256, 0, stream>>>(
            t_h, dinv, row_ptr, col, ew, conv_b + l * 64,
            ln_g + l * 64, ln_b + l * 64, h);
        hin = h;
    }

    // P = h @ W1[0:64] + b1 ; Q = h @ W1[64:128]  (fp16 outputs, one dispatch)
    k_gemm_pq<<<2 * gemm_blocks, 256, 0, stream>>>(h, dw1, db1, dw1 + 64 * 64, P_h, Q_h);

    k_decoder<<<nb_edges, 256, 0, stream>>>(
        P_h, Q_h, src, dst, attr, dw1 + 128 * 64, dw2, db2, dw3, db3, out);
}

// Round 8
// 465.705 us; speedup vs baseline: 2.5713x; 1.0241x over previous
//
#include <hip/hip_runtime.h>
#include <hip/hip_fp16.h>

#define N_NODES 50000
#define N_EDGES 800000
#define HID 64
#define F_EDGE 16
#define LN_EPS 1e-5f
#define SCAN_BLOCKS ((N_NODES + 255) / 256)   // 196

// ---------------- utility: 64-lane wave reduction ----------------
__device__ inline float wave_sum64(float v) {
    #pragma unroll
    for (int o = 32; o > 0; o >>= 1) v += __shfl_xor(v, o, 64);
    return v;
}

// ---------------- CSR build ----------------
__global__ void k_zero_cnt(int* __restrict__ cnt) {
    int i = blockIdx.x * blockDim.x + threadIdx.x;
    if (i < N_NODES) cnt[i] = 0;
}

__global__ void k_count(const int* __restrict__ dst, int* __restrict__ cnt) {
    int e = blockIdx.x * blockDim.x + threadIdx.x;
    if (e < N_EDGES) atomicAdd(&cnt[dst[e]], 1);
}

// stage 1: per-block exclusive scan into row_ptr, block sums into bsum; fused dinv
__global__ void k_scan1(const int* __restrict__ cnt, int* __restrict__ row_ptr,
                        int* __restrict__ bsum, float* __restrict__ dinv) {
    __shared__ int wsum[4];
    int tid = threadIdx.x, lane = tid & 63, w = tid >> 6;
    int i = blockIdx.x * 256 + tid;
    int v = (i < N_NODES) ? cnt[i] : 0;
    if (i < N_NODES) dinv[i] = rsqrtf((float)v + 1.0f);
    int isc = v;
    #pragma unroll
    for (int o = 1; o < 64; o <<= 1) {
        int n = __shfl_up(isc, o, 64);
        if (lane >= o) isc += n;
    }
    if (lane == 63) wsum[w] = isc;
    __syncthreads();
    int woff = 0;
    #pragma unroll
    for (int k = 0; k < 4; k++) woff += (k < w) ? wsum[k] : 0;
    if (i < N_NODES) row_ptr[i] = woff + isc - v;
    if (tid == 255) bsum[blockIdx.x] = woff + isc;
}

// stage 2: single block scans the block sums -> exclusive boff
__global__ void k_scan2(const int* __restrict__ bsum, int* __restrict__ boff) {
    __shared__ int wsum[4];
    int tid = threadIdx.x, lane = tid & 63, w = tid >> 6;
    int v = (tid < SCAN_BLOCKS) ? bsum[tid] : 0;
    int isc = v;
    #pragma unroll
    for (int o = 1; o < 64; o <<= 1) {
        int n = __shfl_up(isc, o, 64);
        if (lane >= o) isc += n;
    }
    if (lane == 63) wsum[w] = isc;
    __syncthreads();
    int woff = 0;
    #pragma unroll
    for (int k = 0; k < 4; k++) woff += (k < w) ? wsum[k] : 0;
    if (tid < SCAN_BLOCKS) boff[tid] = woff + isc - v;
}

// stage 3: apply block offsets, init cursor
__global__ void k_scan3(int* __restrict__ row_ptr, const int* __restrict__ boff,
                        int* __restrict__ cursor) {
    int i = blockIdx.x * blockDim.x + threadIdx.x;
    if (i < N_NODES) {
        int r = row_ptr[i] + boff[i >> 8];
        row_ptr[i] = r;
        cursor[i] = r;
    }
    if (i == 0) row_ptr[N_NODES] = N_EDGES;
}

// fill: single random 4B store per edge (no ew — weights folded into xs pre-scaling)
__global__ void k_fill(const int* __restrict__ src, const int* __restrict__ dst,
                       int* __restrict__ cursor, int* __restrict__ col) {
    int e = blockIdx.x * blockDim.x + threadIdx.x;
    if (e < N_EDGES) {
        int s = src[e], d = dst[e];
        int pos = atomicAdd(&cursor[d], 1);
        col[pos] = s;
    }
}

// ---------------- xs = fp16(dinv * x) ----------------
__global__ void k_xs_init(const float* __restrict__ x, const float* __restrict__ dinv,
                          __half* __restrict__ xs) {
    int i = blockIdx.x * blockDim.x + threadIdx.x;
    if (i < N_NODES * 64) xs[i] = __float2half_rn(x[i] * dinv[i >> 6]);
}

// ---------------- gather: agg[d] = dinv[d] * (sum_{s in N(d)} xs[s] + xs[d]) ----------------
// wave per node; 8 edge-slots x 8 lanes x 16 B (8 halves) per gather instr; col-only preload
__global__ void __launch_bounds__(256)
k_gather_agg(const __half* __restrict__ xs, const float* __restrict__ dinv,
             const int* __restrict__ row_ptr, const int* __restrict__ col,
             float* __restrict__ agg) {
    int gid = blockIdx.x * blockDim.x + threadIdx.x;
    int node = gid >> 6, lane = gid & 63;
    if (node >= N_NODES) return;
    int n0 = __builtin_amdgcn_readfirstlane(node);
    int q = lane >> 3;        // edge slot 0..7
    int c8 = lane & 7;        // channel-octet (channels 8*c8..8*c8+7)
    const float4* x4 = (const float4*)xs;   // 16 B = 8 halves

    float acc[8];
    #pragma unroll
    for (int u = 0; u < 8; u++) acc[u] = 0.0f;

    // self-loop row on slot 0 (weight 1: xs is pre-scaled by dinv)
    if (q == 0) {
        float4 raw = x4[(size_t)n0 * 8 + c8];
        const __half2* hp = (const __half2*)&raw;
        float2 f0 = __half22float2(hp[0]);
        float2 f1 = __half22float2(hp[1]);
        float2 f2 = __half22float2(hp[2]);
        float2 f3 = __half22float2(hp[3]);
        acc[0] = f0.x; acc[1] = f0.y; acc[2] = f1.x; acc[3] = f1.y;
        acc[4] = f2.x; acc[5] = f2.y; acc[6] = f3.x; acc[7] = f3.y;
    }

    int beg = row_ptr[n0], end = row_ptr[n0 + 1];
    int deg = end - beg;

    int cL = 0;
    if (lane < deg) cL = col[beg + lane];
    int steps = (min(deg, 64) + 7) >> 3;

    #pragma unroll 4
    for (int st = 0; st < steps; st++) {
        int idx = 8 * st + q;
        int s = __shfl(cL, idx, 64);               // 0 for masked lanes -> safe addr
        float m = (idx < deg) ? 1.0f : 0.0f;       // mask (no ew anymore)
        float4 raw = x4[(size_t)s * 8 + c8];
        const __half2* hp = (const __half2*)&raw;
        float2 f0 = __half22float2(hp[0]);
        float2 f1 = __half22float2(hp[1]);
        float2 f2 = __half22float2(hp[2]);
        float2 f3 = __half22float2(hp[3]);
        acc[0] = fmaf(f0.x, m, acc[0]); acc[1] = fmaf(f0.y, m, acc[1]);
        acc[2] = fmaf(f1.x, m, acc[2]); acc[3] = fmaf(f1.y, m, acc[3]);
        acc[4] = fmaf(f2.x, m, acc[4]); acc[5] = fmaf(f2.y, m, acc[5]);
        acc[6] = fmaf(f3.x, m, acc[6]); acc[7] = fmaf(f3.y, m, acc[7]);
    }
    // tail deg>64 (rare): slot-parallel direct reads, weight 1
    for (int j = beg + 64 + q; j < end; j += 8) {
        int s = col[j];
        float4 raw = x4[(size_t)s * 8 + c8];
        const __half2* hp = (const __half2*)&raw;
        float2 f0 = __half22float2(hp[0]);
        float2 f1 = __half22float2(hp[1]);
        float2 f2 = __half22float2(hp[2]);
        float2 f3 = __half22float2(hp[3]);
        acc[0] += f0.x; acc[1] += f0.y; acc[2] += f1.x; acc[3] += f1.y;
        acc[4] += f2.x; acc[5] += f2.y; acc[6] += f3.x; acc[7] += f3.y;
    }

    // reduce across the 8 slots (lane bits 3,4,5)
    #pragma unroll
    for (int o = 8; o <= 32; o <<= 1) {
        #pragma unroll
        for (int u = 0; u < 8; u++) acc[u] += __shfl_xor(acc[u], o, 64);
    }

    if (q == 0) {
        float di = dinv[n0];
        float4 y0, y1;
        y0.x = acc[0] * di; y0.y = acc[1] * di; y0.z = acc[2] * di; y0.w = acc[3] * di;
        y1.x = acc[4] * di; y1.y = acc[5] * di; y1.z = acc[6] * di; y1.w = acc[7] * di;
        float4* a4 = (float4*)agg;
        a4[(size_t)n0 * 16 + 2 * c8] = y0;
        a4[(size_t)n0 * 16 + 2 * c8 + 1] = y1;
    }
}

// ---------------- fused: out = relu(LN(agg @ W + cb)) [ * dinv -> fp16 | fp32 ] ----------------
// grid-stride wave per row; W col in VGPRs, agg row via wave-uniform s_load; LN across lanes
__global__ void __launch_bounds__(256)
k_gemm_ln(const float* __restrict__ agg, const float* __restrict__ W,
          const float* __restrict__ cb, const float* __restrict__ g,
          const float* __restrict__ b, const float* __restrict__ dinv,
          __half* __restrict__ xs_out, float* __restrict__ h_out) {
    int lane = threadIdx.x & 63;
    int wid = (blockIdx.x * blockDim.x + threadIdx.x) >> 6;
    int nwaves = (gridDim.x * blockDim.x) >> 6;
    float w[64];
    #pragma unroll
    for (int k = 0; k < 64; k++) w[k] = W[k * 64 + lane];
    float cbl = cb[lane], gl = g[lane], bl = b[lane];
    for (int row = wid; row < N_NODES; row += nwaves) {
        int r = __builtin_amdgcn_readfirstlane(row);
        const float* xr = agg + r * 64;
        float acc = cbl;
        #pragma unroll
        for (int k = 0; k < 64; k++) acc = fmaf(xr[k], w[k], acc);
        float mu = wave_sum64(acc) * (1.0f / 64.0f);
        float d = acc - mu;
        float var = wave_sum64(d * d) * (1.0f / 64.0f);
        float y = fmaxf(fmaf(d * rsqrtf(var + LN_EPS), gl, bl), 0.0f);
        if (xs_out) {
            xs_out[r * 64 + lane] = __float2half_rn(y * dinv[r]);
        } else {
            h_out[r * 64 + lane] = y;
        }
    }
}

// fused P/Q (fp16 out): first half of blocks -> P = h@W1a + b1, second half -> Q = h@W1b
__global__ void __launch_bounds__(256)
k_gemm_pq(const float* __restrict__ hin, const float* __restrict__ Wp,
          const float* __restrict__ bp, const float* __restrict__ Wq,
          __half* __restrict__ P, __half* __restrict__ Q) {
    int half_g = gridDim.x >> 1;
    bool isQ = (blockIdx.x >= half_g);
    const float* W = isQ ? Wq : Wp;
    __half* out = isQ ? Q : P;
    int lane = threadIdx.x & 63;
    int bid = isQ ? (blockIdx.x - half_g) : blockIdx.x;
    int wid = (bid * blockDim.x + threadIdx.x) >> 6;
    int nwaves = (half_g * blockDim.x) >> 6;
    float w[64];
    #pragma unroll
    for (int k = 0; k < 64; k++) w[k] = W[k * 64 + lane];
    float binit = isQ ? 0.0f : bp[lane];
    for (int row = wid; row < N_NODES; row += nwaves) {
        int r = __builtin_amdgcn_readfirstlane(row);
        const float* xr = hin + r * 64;
        float acc = binit;
        #pragma unroll
        for (int k = 0; k < 64; k++) acc = fmaf(xr[k], w[k], acc);
        out[r * 64 + lane] = __float2half_rn(acc);
    }
}

// ---------------- decoder: original edge order, fp16 P/Q gathers ----------------
// RULE: acc[]/acc2[] indices compile-time constant (no scratch spill).
__global__ void __launch_bounds__(256)
k_decoder(const __half* __restrict__ P, const __half* __restrict__ Q,
          const int* __restrict__ src, const int* __restrict__ dst,
          const float* __restrict__ attr,
          const float* __restrict__ W1c,
          const float* __restrict__ W2, const float* __restrict__ b2,
          const float* __restrict__ W3, const float* __restrict__ b3,
          float* __restrict__ out) {
    int e = blockIdx.x * blockDim.x + threadIdx.x;
    if (e >= N_EDGES) return;
    int s = src[e], d = dst[e];

    const float4* ap = (const float4*)(attr + (size_t)e * 16);
    float4 av0 = ap[0], av1 = ap[1], av2 = ap[2], av3 = ap[3];

    float acc[64];
    const float4* Pp = (const float4*)(P + (size_t)s * 64);
    const float4* Qp = (const float4*)(Q + (size_t)d * 64);
    #pragma unroll
    for (int c = 0; c < 8; c++) {
        float4 pv = Pp[c], qv = Qp[c];
        const __half2* ph = (const __half2*)&pv;
        const __half2* qh = (const __half2*)&qv;
        #pragma unroll
        for (int u = 0; u < 4; u++) {
            float2 pf = __half22float2(ph[u]);
            float2 qf = __half22float2(qh[u]);
            acc[8 * c + 2 * u]     = pf.x + qf.x;
            acc[8 * c + 2 * u + 1] = pf.y + qf.y;
        }
    }

    #pragma unroll
    for (int j = 0; j < 64; j++) {
        float a = acc[j];
        a = fmaf(av0.x, W1c[0 * 64 + j], a);
        a = fmaf(av0.y, W1c[1 * 64 + j], a);
        a = fmaf(av0.z, W1c[2 * 64 + j], a);
        a = fmaf(av0.w, W1c[3 * 64 + j], a);
        a = fmaf(av1.x, W1c[4 * 64 + j], a);
        a = fmaf(av1.y, W1c[5 * 64 + j], a);
        a = fmaf(av1.z, W1c[6 * 64 + j], a);
        a = fmaf(av1.w, W1c[7 * 64 + j], a);
        a = fmaf(av2.x, W1c[8 * 64 + j], a);
        a = fmaf(av2.y, W1c[9 * 64 + j], a);
        a = fmaf(av2.z, W1c[10 * 64 + j], a);
        a = fmaf(av2.w, W1c[11 * 64 + j], a);
        a = fmaf(av3.x, W1c[12 * 64 + j], a);
        a = fmaf(av3.y, W1c[13 * 64 + j], a);
        a = fmaf(av3.z, W1c[14 * 64 + j], a);
        a = fmaf(av3.w, W1c[15 * 64 + j], a);
        acc[j] = fmaxf(a, 0.0f);
    }

    float acc2[32];
    #pragma unroll
    for (int j = 0; j < 32; j++) acc2[j] = b2[j];
    #pragma unroll
    for (int k = 0; k < 64; k++) {
        float hk = acc[k];
        #pragma unroll
        for (int j = 0; j < 32; j++)
            acc2[j] = fmaf(hk, W2[k * 32 + j], acc2[j]);
    }

    float o = b3[0];
    #pragma unroll
    for (int j = 0; j < 32; j++)
        o = fmaf(fmaxf(acc2[j], 0.0f), W3[j], o);
    out[e] = o;
}

// ---------------- launch ----------------
extern "C" void kernel_launch(void* const* d_in, const int* in_sizes, int n_in,
                              void* d_out, int out_size, void* d_ws, size_t ws_size,
                              hipStream_t stream) {
    const float* x      = (const float*)d_in[0];
    const int*   ei     = (const int*)d_in[1];
    const float* attr   = (const float*)d_in[2];
    const float* conv_w = (const float*)d_in[3];
    const float* conv_b = (const float*)d_in[4];
    const float* ln_g   = (const float*)d_in[5];
    const float* ln_b   = (const float*)d_in[6];
    const float* dw1    = (const float*)d_in[7];
    const float* db1    = (const float*)d_in[8];
    const float* dw2    = (const float*)d_in[9];
    const float* db2    = (const float*)d_in[10];
    const float* dw3    = (const float*)d_in[11];
    const float* db3    = (const float*)d_in[12];
    float* out = (float*)d_out;

    const int* src = ei;
    const int* dst = ei + N_EDGES;

    char* p = (char*)d_ws;
    float*  dinv    = (float*)p;  p += sizeof(float) * N_NODES;
    float*  agg     = (float*)p;  p += sizeof(float) * (size_t)N_NODES * 64;
    float*  h3      = (float*)p;  p += sizeof(float) * (size_t)N_NODES * 64;
    __half* xs      = (__half*)p; p += sizeof(__half) * (size_t)N_NODES * 64;
    __half* P_h     = (__half*)p; p += sizeof(__half) * (size_t)N_NODES * 64;
    __half* Q_h     = (__half*)p; p += sizeof(__half) * (size_t)N_NODES * 64;
    int*    cnt     = (int*)p;    p += sizeof(int) * N_NODES;
    int*    cursor  = (int*)p;    p += sizeof(int) * N_NODES;
    int*    row_ptr = (int*)p;    p += sizeof(int) * (N_NODES + 1);
    int*    col     = (int*)p;    p += sizeof(int) * N_EDGES;
    int*    bsum    = (int*)p;    p += sizeof(int) * 256;
    int*    boff    = (int*)p;    p += sizeof(int) * 256;

    const int nb_nodes = (N_NODES + 255) / 256;
    const int nb_edges = (N_EDGES + 255) / 256;
    const int nb_elems = (N_NODES * 64 + 255) / 256;

    k_zero_cnt<<<nb_nodes, 256, 0, stream>>>(cnt);
    k_count<<<nb_edges, 256, 0, stream>>>(dst, cnt);
    k_scan1<<<SCAN_BLOCKS, 256, 0, stream>>>(cnt, row_ptr, bsum, dinv);
    k_scan2<<<1, 256, 0, stream>>>(bsum, boff);
    k_scan3<<<nb_nodes, 256, 0, stream>>>(row_ptr, boff, cursor);
    k_fill<<<nb_edges, 256, 0, stream>>>(src, dst, cursor, col);
    k_xs_init<<<nb_elems, 256, 0, stream>>>(x, dinv, xs);

    const int gemm_blocks = 1024;
    const int gather_blocks = N_NODES / 4;   // wave per node, 4 waves/block

    for (int l = 0; l < 3; l++) {
        k_gather_agg<<<gather_blocks, 256, 0, stream>>>(xs, dinv, row_ptr, col, agg);
        bool last = (l == 2);
        k_gemm_ln<<<gemm_blocks, 256, 0, stream>>>(
            agg, conv_w + l * 4096, conv_b + l * 64,
            ln_g + l * 64, ln_b + l * 64, dinv,
            last ? (__half*)nullptr : xs, last ? h3 : (float*)nullptr);
    }

    // P = h3 @ W1[0:64] + b1 ; Q = h3 @ W1[64:128]  (fp16 outputs, one dispatch)
    k_gemm_pq<<<2 * gemm_blocks, 256, 0, stream>>>(h3, dw1, db1, dw1 + 64 * 64, P_h, Q_h);

    k_decoder<<<nb_edges, 256, 0, stream>>>(
        P_h, Q_h, src, dst, attr, dw1 + 128 * 64, dw2, db2, dw3, db3, out);
}